// Round 8
// baseline (198.912 us; speedup 1.0000x reference)
//
#include <hip/hip_runtime.h>
#include <hip/hip_bf16.h>

typedef unsigned short u16;
typedef __attribute__((ext_vector_type(8))) short bf16x8;
typedef __attribute__((ext_vector_type(8))) unsigned short u16x8;
typedef __attribute__((ext_vector_type(4))) float f32x4;

#define MFMA16(a,b,c) __builtin_amdgcn_mfma_f32_16x16x32_bf16(a,b,c,0,0,0)

__device__ __forceinline__ u16 f2bf(float f) {
  union { float f; unsigned int u; } v; v.f = f;
  unsigned int r = v.u + 0x7fffu + ((v.u >> 16) & 1u);  // RNE, finite inputs
  return (u16)(r >> 16);
}
__device__ __forceinline__ float bf2f(u16 u) {
  union { unsigned int i; float f; } v; v.i = ((unsigned int)u) << 16; return v.f;
}

__device__ __forceinline__ void gld16(const void* g, void* l) {
  __builtin_amdgcn_global_load_lds((const __attribute__((address_space(1))) void*)g,
                                   (__attribute__((address_space(3))) void*)l, 16, 0, 0);
}

// ---------------- fused prep: cast4 (blocks 0..6143) + ttrans qkv + ttrans proj ----------------
__device__ __forceinline__ void ttrans_body(const float* __restrict__ in, u16* __restrict__ out,
                                            int K, int N, int blk, int tid, u16 T[64][65]) {
  const int ntx = N >> 6;
  const int tx = blk % ntx, ty = blk / ntx;
  const int n0 = tx * 64, k0 = ty * 64;
  #pragma unroll
  for (int p = 0; p < 4; ++p) {
    int idx = p * 256 + tid;            // 0..1023
    int r = idx >> 4, ch = idx & 15;
    float4 v = *reinterpret_cast<const float4*>(in + (size_t)(k0 + r) * N + n0 + ch * 4);
    T[r][ch * 4 + 0] = f2bf(v.x);
    T[r][ch * 4 + 1] = f2bf(v.y);
    T[r][ch * 4 + 2] = f2bf(v.z);
    T[r][ch * 4 + 3] = f2bf(v.w);
  }
  __syncthreads();
  #pragma unroll
  for (int p = 0; p < 2; ++p) {
    int idx = p * 256 + tid;            // 0..511
    int rr = idx >> 3, ch = idx & 7;
    u16x8 o;
    #pragma unroll
    for (int e = 0; e < 8; ++e) o[e] = T[ch * 8 + e][rr];
    *reinterpret_cast<u16x8*>(out + (size_t)(n0 + rr) * K + k0 + ch * 8) = o;
  }
}

__global__ void prep(const float* __restrict__ hs, u16* __restrict__ hs_bf,
                     const float* __restrict__ qkv_w, u16* __restrict__ qkvwT,
                     const float* __restrict__ proj_w, u16* __restrict__ projwT) {
  __shared__ u16 T[64][65];
  const int blk = blockIdx.x, tid = threadIdx.x;
  if (blk < 6144) {
    int i = blk * 256 + tid;            // n4 = 1572864 = 6144*256 exact
    float4 v = reinterpret_cast<const float4*>(hs)[i];
    ushort4 o; o.x = f2bf(v.x); o.y = f2bf(v.y); o.z = f2bf(v.z); o.w = f2bf(v.w);
    reinterpret_cast<ushort4*>(hs_bf)[i] = o;
  } else if (blk < 6360) {
    ttrans_body(qkv_w, qkvwT, 384, 2304, blk - 6144, tid, T);
  } else {
    ttrans_body(proj_w, projwT, 768, 768, blk - 6360, tid, T);
  }
}

// ---------------- GEMM: C[M,N] = A[M,K] * Bt[N,K]^T + bias ----------------
// 128x128 tile, BK=32, double-buffered LDS, counted-vmcnt prefetch, XCD swizzle.
template<int EPI>
__launch_bounds__(256)
__global__ void gemm_bt(const u16* __restrict__ A, const u16* __restrict__ Bt,
                        const float* __restrict__ bias,
                        u16* __restrict__ oq, u16* __restrict__ ok, u16* __restrict__ ov,
                        float* __restrict__ of, int K, int nbx, int cpx) {
  __shared__ __align__(16) u16 As[2][128 * 32];
  __shared__ __align__(16) u16 Bs[2][128 * 32];
  const int id = blockIdx.x;
  const int id2 = (id & 7) * cpx + (id >> 3);   // cpx = nwg/8
  const int bx = id2 % nbx, by = id2 / nbx;
  const int tid = threadIdx.x;
  const int wave = tid >> 6, lane = tid & 63;
  const int c = lane & 15, g = lane >> 4;
  const int brow = by * 128, bcol = bx * 128;
  const int wr = (wave >> 1) * 64, wc = (wave & 1) * 64;
  f32x4 acc[4][4] = {};
  const int srow = wave * 32 + (lane >> 2);
  const int scol = (lane & 3) * 8;
  const u16* agp0 = A  + (size_t)(brow + srow) * K + scol;
  const u16* agp1 = A  + (size_t)(brow + srow + 16) * K + scol;
  const u16* bgp0 = Bt + (size_t)(bcol + srow) * K + scol;
  const u16* bgp1 = Bt + (size_t)(bcol + srow + 16) * K + scol;
  const int lo0 = wave * 1024, lo1 = wave * 1024 + 512;
  const int nk = K >> 5;
  gld16(agp0, &As[0][lo0]);
  gld16(agp1, &As[0][lo1]);
  gld16(bgp0, &Bs[0][lo0]);
  gld16(bgp1, &Bs[0][lo1]);
  for (int ks = 0; ks < nk; ++ks) {
    const int cur = ks & 1;
    if (ks + 1 < nk) {
      const int k1 = (ks + 1) << 5;
      gld16(agp0 + k1, &As[cur ^ 1][lo0]);
      gld16(agp1 + k1, &As[cur ^ 1][lo1]);
      gld16(bgp0 + k1, &Bs[cur ^ 1][lo0]);
      gld16(bgp1 + k1, &Bs[cur ^ 1][lo1]);
      asm volatile("s_waitcnt vmcnt(4)" ::: "memory");
    } else {
      asm volatile("s_waitcnt vmcnt(0)" ::: "memory");
    }
    __builtin_amdgcn_s_barrier();
    __builtin_amdgcn_sched_barrier(0);
    bf16x8 af[4], bfr[4];
    #pragma unroll
    for (int mi = 0; mi < 4; ++mi)
      af[mi] = *reinterpret_cast<const bf16x8*>(&As[cur][(wr + mi * 16 + c) * 32 + g * 8]);
    #pragma unroll
    for (int ni = 0; ni < 4; ++ni)
      bfr[ni] = *reinterpret_cast<const bf16x8*>(&Bs[cur][(wc + ni * 16 + c) * 32 + g * 8]);
    #pragma unroll
    for (int mi = 0; mi < 4; ++mi)
      #pragma unroll
      for (int ni = 0; ni < 4; ++ni)
        acc[mi][ni] = MFMA16(af[mi], bfr[ni], acc[mi][ni]);
    __builtin_amdgcn_sched_barrier(0);
    __builtin_amdgcn_s_barrier();
  }
  #pragma unroll
  for (int mi = 0; mi < 4; ++mi) {
    #pragma unroll
    for (int ni = 0; ni < 4; ++ni) {
      const int col = bcol + wc + ni * 16 + c;
      const float bz = bias[col];
      #pragma unroll
      for (int i = 0; i < 4; ++i) {
        const int row = brow + wr + mi * 16 + g * 4 + i;
        float v = acc[mi][ni][i] + bz;
        if (EPI == 0) {
          if (col < 768)       oq[(size_t)row * 768 + col]        = f2bf(v);
          else if (col < 1536) ok[(size_t)row * 768 + col - 768]  = f2bf(v);
          else                 ov[(size_t)row * 768 + col - 1536] = f2bf(v);
        } else {
          of[(size_t)row * 768 + col] = v;
        }
      }
    }
  }
}

// ---------------- 2x2 max-pool on q (bf16) + fold scale*log2e ----------------
__global__ void qpool(const u16* __restrict__ qf, u16* __restrict__ qp) {
  int idx = blockIdx.x * blockDim.x + threadIdx.x;
  if (idx >= 4096 * 96) return;
  const float SC = 0.14724744f;  // 96^-0.5 * log2(e)
  int r = idx / 96, cc = (idx - r * 96) * 8;
  int b = r >> 10, ij = r & 1023, ii = ij >> 5, jj = ij & 31;
  const size_t base = ((size_t)b * 4096 + (size_t)ii * 128 + jj * 2) * 768 + cc;
  u16x8 x0 = *reinterpret_cast<const u16x8*>(qf + base);
  u16x8 x1 = *reinterpret_cast<const u16x8*>(qf + base + 768);
  u16x8 x2 = *reinterpret_cast<const u16x8*>(qf + base + 64 * 768);
  u16x8 x3 = *reinterpret_cast<const u16x8*>(qf + base + 65 * 768);
  u16x8 o;
  #pragma unroll
  for (int e = 0; e < 8; ++e) {
    float mv = bf2f(x0[e]);
    mv = fmaxf(mv, bf2f(x1[e]));
    mv = fmaxf(mv, bf2f(x2[e]));
    mv = fmaxf(mv, bf2f(x3[e]));
    o[e] = f2bf(mv * SC);
  }
  *reinterpret_cast<u16x8*>(qp + (size_t)r * 768 + cc) = o;
}

// ---------------- V transpose: vbuf[16384][768] -> vT[(bh*96+d)*4096 + s] ----------------
__global__ void vtrans(const u16* __restrict__ vbuf, u16* __restrict__ vT) {
  __shared__ u16 T[64][97];
  const int blk = blockIdx.x;           // (bh)*64 + tile
  const int st = blk & 63, bh = blk >> 6;
  const int b = bh >> 3, h = bh & 7;
  const int tid = threadIdx.x;
  const u16* src = vbuf + ((size_t)(b * 4096 + st * 64)) * 768 + h * 96;
  #pragma unroll
  for (int j = 0; j < 3; ++j) {
    int p = tid + 256 * j;              // 0..767
    int r = p / 12, ch = p - r * 12;
    u16x8 v = *reinterpret_cast<const u16x8*>(src + (size_t)r * 768 + ch * 8);
    #pragma unroll
    for (int e = 0; e < 8; ++e) T[r][ch * 8 + e] = v[e];
  }
  __syncthreads();
  u16* dst = vT + ((size_t)(bh * 96)) * 4096 + st * 64;
  #pragma unroll
  for (int j = 0; j < 3; ++j) {
    int oc = tid + 256 * j;             // 0..767
    int d = oc >> 3, part = oc & 7;
    u16x8 o;
    #pragma unroll
    for (int e = 0; e < 8; ++e) o[e] = T[part * 8 + e][d];
    *reinterpret_cast<u16x8*>(dst + (size_t)d * 4096 + part * 8) = o;
  }
}

// ---------------- flash attention: 8 waves, in-block key-split, in-block combine ----------------
// grid 512: blk = bh*16 + qt. Wave w: sq = w>>2 (key half), wq = w&3 (q sub-tile).
// LDS arena (u16 idx): K0@0, V0@6144, K1@12288, V1@18432, Pl@24576 (8x1024). 64KB total.
// Epilogue overlays: Cb f32[4][16][96] @0, Ml f32[4][16][2] @24576 (double-barrier).
__launch_bounds__(512, 4)
__global__ void flash6(const u16* __restrict__ Qp, const u16* __restrict__ Kb,
                       const u16* __restrict__ Vtg, u16* __restrict__ aout) {
  const int blk = blockIdx.x;
  const int qt = blk & 15, bh = blk >> 4;
  const int b = bh >> 3, h = bh & 7;
  __shared__ __align__(16) u16 Sh[32768];
  const int tid = threadIdx.x, w = tid >> 6, lane = tid & 63;
  const int sq = w >> 2, wq = w & 3;
  const int c = lane & 15, g = lane >> 4;
  const int kbase = sq * 12288;         // this half's K region
  const int vbase = 6144 + sq * 12288;  // this half's V region
  // Q fragments (pre-scaled by scale*log2e); q = c
  const u16* qb = Qp + ((size_t)(b * 1024 + qt * 64 + wq * 16 + c)) * 768 + h * 96;
  bf16x8 qf[3];
  #pragma unroll
  for (int kc = 0; kc < 3; ++kc)
    qf[kc] = *reinterpret_cast<const bf16x8*>(qb + kc * 32 + g * 8);
  // staging thread-constants: 4 waves of the half cover 768 16B-chunks
  int koff[3], voff[3], loff[3];
  #pragma unroll
  for (int j = 0; j < 3; ++j) {
    int p = wq * 192 + j * 64 + lane;   // 0..767
    int r = p / 12, ch = p - r * 12;    // K: row r, chunk ch (12 x 16B per row)
    koff[j] = r * 768 + ch * 8;
    int d = p >> 3, vch = p & 7;        // V: row d (8 x 16B), pre-swizzled src
    voff[j] = d * 4096 + ((vch ^ (d & 7)) * 8);
    loff[j] = (wq * 192 + j * 64) * 8;  // wave-uniform LDS base within region
  }
  const u16* kb0 = Kb + ((size_t)(b * 4096 + sq * 2048)) * 768 + h * 96;
  const u16* vb0 = Vtg + ((size_t)(bh * 96)) * 4096 + sq * 2048;
  float m = -1e30f, l = 0.f;            // per-lane, q = c domain (replicated over g)
  f32x4 acc[6] = {};
  const int sw = (c & 7) << 3;          // Vs read-side chunk swizzle (u16 index)
  const int psw = (c & 7) << 1;         // Pl 8B-chunk swizzle
  const int pbase = 24576 + w * 1024 + c * 64;
  for (int kt = 0; kt < 32; ++kt) {
    __syncthreads();
    #pragma unroll
    for (int j = 0; j < 3; ++j) gld16(kb0 + (size_t)kt * 49152 + koff[j], &Sh[kbase + loff[j]]);
    #pragma unroll
    for (int j = 0; j < 3; ++j) gld16(vb0 + kt * 64 + voff[j], &Sh[vbase + loff[j]]);
    __syncthreads();
    // swapped QK^T: st[kt4] = S^T[key = kt4*16 + g*4 + i][q = c]
    f32x4 st[4] = {};
    #pragma unroll
    for (int kc = 0; kc < 3; ++kc)
      #pragma unroll
      for (int kt4 = 0; kt4 < 4; ++kt4) {
        bf16x8 kf = *reinterpret_cast<const bf16x8*>(&Sh[kbase + (kt4 * 16 + c) * 96 + kc * 32 + g * 8]);
        st[kt4] = MFMA16(kf, qf[kc], st[kt4]);
      }
    float pmax = st[0][0];
    #pragma unroll
    for (int kt4 = 0; kt4 < 4; ++kt4)
      #pragma unroll
      for (int i = 0; i < 4; ++i)
        pmax = fmaxf(pmax, st[kt4][i]);
    pmax = fmaxf(pmax, __shfl_xor(pmax, 16));
    pmax = fmaxf(pmax, __shfl_xor(pmax, 32));
    if (__any(pmax > m + 8.0f)) {
      float mn = fmaxf(m, pmax);
      float esc = exp2f(m - mn);
      m = mn;
      l *= esc;
      float er[4];
      #pragma unroll
      for (int i = 0; i < 4; ++i) er[i] = __shfl(esc, g * 4 + i);
      #pragma unroll
      for (int dc = 0; dc < 6; ++dc)
        #pragma unroll
        for (int i = 0; i < 4; ++i)
          acc[dc][i] *= er[i];
    }
    float ps = 0.f;
    #pragma unroll
    for (int kt4 = 0; kt4 < 4; ++kt4)
      #pragma unroll
      for (int i = 0; i < 4; ++i) {
        float p = exp2f(st[kt4][i] - m);
        st[kt4][i] = p;
        ps += p;
      }
    ps += __shfl_xor(ps, 16);
    ps += __shfl_xor(ps, 32);
    l += ps;
    #pragma unroll
    for (int kt4 = 0; kt4 < 4; ++kt4) {
      unsigned int u0, u1;
      asm("v_cvt_pk_bf16_f32 %0, %1, %2" : "=v"(u0) : "v"(st[kt4][0]), "v"(st[kt4][1]));
      asm("v_cvt_pk_bf16_f32 %0, %1, %2" : "=v"(u1) : "v"(st[kt4][2]), "v"(st[kt4][3]));
      const int chunk = (kt4 * 4 + g) ^ psw;
      *reinterpret_cast<uint2*>(&Sh[pbase + chunk * 4]) = make_uint2(u0, u1);
    }
    asm volatile("s_waitcnt lgkmcnt(0)" ::: "memory");
    #pragma unroll
    for (int kh = 0; kh < 2; ++kh) {
      const int rchunk = (kh * 8 + g * 2) ^ psw;
      bf16x8 pf = *reinterpret_cast<const bf16x8*>(&Sh[pbase + rchunk * 4]);
      #pragma unroll
      for (int dc = 0; dc < 6; ++dc) {
        bf16x8 vf = *reinterpret_cast<const bf16x8*>(&Sh[vbase + (dc * 16 + c) * 64 + ((kh * 32 + g * 8) ^ sw)]);
        acc[dc] = MFMA16(pf, vf, acc[dc]);
      }
    }
  }
  // ---- in-block combine of the two key-halves ----
  __syncthreads();                       // all K/V/Pl reads done; safe to overlay
  float* Cb = (float*)&Sh[0];            // [4][16][96] f32 = 24KB (overlays K0/V0)
  float* Ml = (float*)&Sh[24576];        // [4][16][2] f32 (overlays Pl)
  if (sq == 1) {
    #pragma unroll
    for (int dc = 0; dc < 6; ++dc)
      #pragma unroll
      for (int i = 0; i < 4; ++i)
        Cb[(wq * 16 + g * 4 + i) * 96 + dc * 16 + c] = acc[dc][i];
    if (lane < 16) {
      Ml[(wq * 16 + lane) * 2]     = m;
      Ml[(wq * 16 + lane) * 2 + 1] = l;
    }
  }
  __syncthreads();
  if (sq == 0) {
    u16* ob = aout + (size_t)(b * 1024 + qt * 64 + wq * 16) * 768 + h * 96;
    #pragma unroll
    for (int i = 0; i < 4; ++i) {
      const int q = g * 4 + i;
      float m0q = __shfl(m, q), l0q = __shfl(l, q);
      float m1q = Ml[(wq * 16 + q) * 2], l1q = Ml[(wq * 16 + q) * 2 + 1];
      float M = fmaxf(m0q, m1q);
      float e0 = exp2f(m0q - M), e1 = exp2f(m1q - M);
      float inv = 1.f / (l0q * e0 + l1q * e1);
      #pragma unroll
      for (int dc = 0; dc < 6; ++dc) {
        float a1 = Cb[(wq * 16 + q) * 96 + dc * 16 + c];
        ob[(size_t)q * 768 + dc * 16 + c] = f2bf((acc[dc][i] * e0 + a1 * e1) * inv);
      }
    }
  }
}

extern "C" void kernel_launch(void* const* d_in, const int* in_sizes, int n_in,
                              void* d_out, int out_size, void* d_ws, size_t ws_size,
                              hipStream_t stream) {
  const float* hs     = (const float*)d_in[0];
  const float* qkv_w  = (const float*)d_in[1];
  const float* qkv_b  = (const float*)d_in[2];
  const float* proj_w = (const float*)d_in[3];
  const float* proj_b = (const float*)d_in[4];
  float* out = (float*)d_out;

  u16* hs_bf  = (u16*)d_ws;                 // 6291456 u16
  u16* qkvwT  = hs_bf  + 6291456;           // 884736
  u16* projwT = qkvwT  + 884736;            // 589824
  u16* qfull  = projwT + 589824;            // 12582912 (dead after qpool) -> vT
  u16* kbuf   = qfull  + 12582912;          // 12582912
  u16* vbuf   = kbuf   + 12582912;          // 12582912
  u16* qpol   = vbuf   + 12582912;          // 3145728
  u16* aout   = qpol   + 3145728;           // 3145728

  u16* vT     = qfull;                      // 32*96*4096 = 12582912 u16, exact fit

  prep<<<6504, 256, 0, stream>>>(hs, hs_bf, qkv_w, qkvwT, proj_w, projwT);

  gemm_bt<0><<<2304, 256, 0, stream>>>(hs_bf, qkvwT, qkv_b,
                                       qfull, kbuf, vbuf, nullptr, 384, 18, 288);
  qpool<<<1536, 256, 0, stream>>>(qfull, qpol);
  vtrans<<<2048, 256, 0, stream>>>(vbuf, vT);
  flash6<<<512, 512, 0, stream>>>(qpol, kbuf, vT, aout);
  gemm_bt<1><<<192, 256, 0, stream>>>(aout, projwT, proj_b,
                                      nullptr, nullptr, nullptr, out, 768, 6, 24);
}

// Round 9
// 186.657 us; speedup vs baseline: 1.0657x; 1.0657x over previous
//
#include <hip/hip_runtime.h>
#include <hip/hip_bf16.h>

typedef unsigned short u16;
typedef __attribute__((ext_vector_type(8))) short bf16x8;
typedef __attribute__((ext_vector_type(8))) unsigned short u16x8;
typedef __attribute__((ext_vector_type(4))) float f32x4;

#define MFMA16(a,b,c) __builtin_amdgcn_mfma_f32_16x16x32_bf16(a,b,c,0,0,0)

__device__ __forceinline__ u16 f2bf(float f) {
  union { float f; unsigned int u; } v; v.f = f;
  unsigned int r = v.u + 0x7fffu + ((v.u >> 16) & 1u);  // RNE, finite inputs
  return (u16)(r >> 16);
}
__device__ __forceinline__ float bf2f(u16 u) {
  union { unsigned int i; float f; } v; v.i = ((unsigned int)u) << 16; return v.f;
}

__device__ __forceinline__ void gld16(const void* g, void* l) {
  __builtin_amdgcn_global_load_lds((const __attribute__((address_space(1))) void*)g,
                                   (__attribute__((address_space(3))) void*)l, 16, 0, 0);
}

// ---------------- fused prep: cast4 (blocks 0..6143) + ttrans qkv + ttrans proj ----------------
__device__ __forceinline__ void ttrans_body(const float* __restrict__ in, u16* __restrict__ out,
                                            int K, int N, int blk, int tid, u16 T[64][65]) {
  const int ntx = N >> 6;
  const int tx = blk % ntx, ty = blk / ntx;
  const int n0 = tx * 64, k0 = ty * 64;
  #pragma unroll
  for (int p = 0; p < 4; ++p) {
    int idx = p * 256 + tid;            // 0..1023
    int r = idx >> 4, ch = idx & 15;
    float4 v = *reinterpret_cast<const float4*>(in + (size_t)(k0 + r) * N + n0 + ch * 4);
    T[r][ch * 4 + 0] = f2bf(v.x);
    T[r][ch * 4 + 1] = f2bf(v.y);
    T[r][ch * 4 + 2] = f2bf(v.z);
    T[r][ch * 4 + 3] = f2bf(v.w);
  }
  __syncthreads();
  #pragma unroll
  for (int p = 0; p < 2; ++p) {
    int idx = p * 256 + tid;            // 0..511
    int rr = idx >> 3, ch = idx & 7;
    u16x8 o;
    #pragma unroll
    for (int e = 0; e < 8; ++e) o[e] = T[ch * 8 + e][rr];
    *reinterpret_cast<u16x8*>(out + (size_t)(n0 + rr) * K + k0 + ch * 8) = o;
  }
}

__global__ void prep(const float* __restrict__ hs, u16* __restrict__ hs_bf,
                     const float* __restrict__ qkv_w, u16* __restrict__ qkvwT,
                     const float* __restrict__ proj_w, u16* __restrict__ projwT) {
  __shared__ u16 T[64][65];
  const int blk = blockIdx.x, tid = threadIdx.x;
  if (blk < 6144) {
    int i = blk * 256 + tid;            // n4 = 1572864 = 6144*256 exact
    float4 v = reinterpret_cast<const float4*>(hs)[i];
    ushort4 o; o.x = f2bf(v.x); o.y = f2bf(v.y); o.z = f2bf(v.z); o.w = f2bf(v.w);
    reinterpret_cast<ushort4*>(hs_bf)[i] = o;
  } else if (blk < 6360) {
    ttrans_body(qkv_w, qkvwT, 384, 2304, blk - 6144, tid, T);
  } else {
    ttrans_body(proj_w, projwT, 768, 768, blk - 6360, tid, T);
  }
}

// ---------------- GEMM: C[M,N] = A[M,K] * Bt[N,K]^T + bias ----------------
// 128x128 tile, BK=32, dbuf LDS, counted-vmcnt prefetch, XCD swizzle.
// EPI 0 (qkv): q columns (bcol<768) -> fused 2x2 maxpool * SC -> qp (bf16);
//              k/v columns -> kbuf/vbuf bf16. EPI 1: fp32 out (proj).
template<int EPI>
__launch_bounds__(256)
__global__ void gemm_bt(const u16* __restrict__ A, const u16* __restrict__ Bt,
                        const float* __restrict__ bias,
                        u16* __restrict__ qp, u16* __restrict__ ok, u16* __restrict__ ov,
                        float* __restrict__ of, int K, int nbx, int cpx) {
  __shared__ __align__(16) u16 As[2][128 * 32];
  __shared__ __align__(16) u16 Bs[2][128 * 32];
  const int id = blockIdx.x;
  const int id2 = (id & 7) * cpx + (id >> 3);   // cpx = nwg/8
  const int bx = id2 % nbx, by = id2 / nbx;
  const int tid = threadIdx.x;
  const int wave = tid >> 6, lane = tid & 63;
  const int c = lane & 15, g = lane >> 4;
  const int brow = by * 128, bcol = bx * 128;
  const int wr = (wave >> 1) * 64, wc = (wave & 1) * 64;
  f32x4 acc[4][4] = {};
  const int srow = wave * 32 + (lane >> 2);
  const int scol = (lane & 3) * 8;
  const u16* agp0 = A  + (size_t)(brow + srow) * K + scol;
  const u16* agp1 = A  + (size_t)(brow + srow + 16) * K + scol;
  const u16* bgp0 = Bt + (size_t)(bcol + srow) * K + scol;
  const u16* bgp1 = Bt + (size_t)(bcol + srow + 16) * K + scol;
  const int lo0 = wave * 1024, lo1 = wave * 1024 + 512;
  const int nk = K >> 5;
  gld16(agp0, &As[0][lo0]);
  gld16(agp1, &As[0][lo1]);
  gld16(bgp0, &Bs[0][lo0]);
  gld16(bgp1, &Bs[0][lo1]);
  for (int ks = 0; ks < nk; ++ks) {
    const int cur = ks & 1;
    if (ks + 1 < nk) {
      const int k1 = (ks + 1) << 5;
      gld16(agp0 + k1, &As[cur ^ 1][lo0]);
      gld16(agp1 + k1, &As[cur ^ 1][lo1]);
      gld16(bgp0 + k1, &Bs[cur ^ 1][lo0]);
      gld16(bgp1 + k1, &Bs[cur ^ 1][lo1]);
      asm volatile("s_waitcnt vmcnt(4)" ::: "memory");
    } else {
      asm volatile("s_waitcnt vmcnt(0)" ::: "memory");
    }
    __builtin_amdgcn_s_barrier();
    __builtin_amdgcn_sched_barrier(0);
    bf16x8 af[4], bfr[4];
    #pragma unroll
    for (int mi = 0; mi < 4; ++mi)
      af[mi] = *reinterpret_cast<const bf16x8*>(&As[cur][(wr + mi * 16 + c) * 32 + g * 8]);
    #pragma unroll
    for (int ni = 0; ni < 4; ++ni)
      bfr[ni] = *reinterpret_cast<const bf16x8*>(&Bs[cur][(wc + ni * 16 + c) * 32 + g * 8]);
    #pragma unroll
    for (int mi = 0; mi < 4; ++mi)
      #pragma unroll
      for (int ni = 0; ni < 4; ++ni)
        acc[mi][ni] = MFMA16(af[mi], bfr[ni], acc[mi][ni]);
    __builtin_amdgcn_sched_barrier(0);
    __builtin_amdgcn_s_barrier();
  }
  if (EPI == 0 && bcol < 768) {
    // ---- fused 2x2 maxpool: block = rows (h0,h0+1) x all w; pooled rows hq*32+wq ----
    const float SC = 0.14724744f;       // 96^-0.5 * log2(e)
    float* P = (float*)&As[0][0];       // overlay dead As: [2][32][64] f32 = 16KB
    float m01[4][4], m23[4][4];
    #pragma unroll
    for (int mi = 0; mi < 4; ++mi)
      #pragma unroll
      for (int ni = 0; ni < 4; ++ni) {
        m01[mi][ni] = fmaxf(acc[mi][ni][0], acc[mi][ni][1]);
        m23[mi][ni] = fmaxf(acc[mi][ni][2], acc[mi][ni][3]);
      }
    if (wr == 64) {                     // h0+1 half: publish partials
      #pragma unroll
      for (int mi = 0; mi < 4; ++mi)
        #pragma unroll
        for (int ni = 0; ni < 4; ++ni) {
          const int pw = mi * 8 + g * 2;
          P[(wave & 1) * 2048 + pw * 64 + ni * 16 + c]       = m01[mi][ni];
          P[(wave & 1) * 2048 + (pw + 1) * 64 + ni * 16 + c] = m23[mi][ni];
        }
    }
    __syncthreads();
    if (wr == 0) {                      // h0 half: combine + write qpol
      const int b = brow >> 12;
      const int hq = (brow >> 7) & 31;
      const size_t rbase = (size_t)(b * 1024 + hq * 32);
      #pragma unroll
      for (int mi = 0; mi < 4; ++mi)
        #pragma unroll
        for (int ni = 0; ni < 4; ++ni) {
          const int col = bcol + wc + ni * 16 + c;
          const float bz = bias[col];
          const int pw = mi * 8 + g * 2;
          float v0 = fmaxf(m01[mi][ni], P[(wave & 1) * 2048 + pw * 64 + ni * 16 + c]);
          float v1 = fmaxf(m23[mi][ni], P[(wave & 1) * 2048 + (pw + 1) * 64 + ni * 16 + c]);
          qp[(rbase + pw) * 768 + col]     = f2bf((v0 + bz) * SC);
          qp[(rbase + pw + 1) * 768 + col] = f2bf((v1 + bz) * SC);
        }
    }
    return;
  }
  #pragma unroll
  for (int mi = 0; mi < 4; ++mi) {
    #pragma unroll
    for (int ni = 0; ni < 4; ++ni) {
      const int col = bcol + wc + ni * 16 + c;
      const float bz = bias[col];
      #pragma unroll
      for (int i = 0; i < 4; ++i) {
        const int row = brow + wr + mi * 16 + g * 4 + i;
        float v = acc[mi][ni][i] + bz;
        if (EPI == 0) {
          if (col < 1536) ok[(size_t)row * 768 + col - 768]  = f2bf(v);
          else            ov[(size_t)row * 768 + col - 1536] = f2bf(v);
        } else {
          of[(size_t)row * 768 + col] = v;
        }
      }
    }
  }
}

// ---------------- V transpose: vbuf[16384][768] -> vT[(bh*96+d)*4096 + s] ----------------
__global__ void vtrans(const u16* __restrict__ vbuf, u16* __restrict__ vT) {
  __shared__ u16 T[64][97];
  const int blk = blockIdx.x;           // (bh)*64 + tile
  const int st = blk & 63, bh = blk >> 6;
  const int b = bh >> 3, h = bh & 7;
  const int tid = threadIdx.x;
  const u16* src = vbuf + ((size_t)(b * 4096 + st * 64)) * 768 + h * 96;
  #pragma unroll
  for (int j = 0; j < 3; ++j) {
    int p = tid + 256 * j;              // 0..767
    int r = p / 12, ch = p - r * 12;
    u16x8 v = *reinterpret_cast<const u16x8*>(src + (size_t)r * 768 + ch * 8);
    #pragma unroll
    for (int e = 0; e < 8; ++e) T[r][ch * 8 + e] = v[e];
  }
  __syncthreads();
  u16* dst = vT + ((size_t)(bh * 96)) * 4096 + st * 64;
  #pragma unroll
  for (int j = 0; j < 3; ++j) {
    int oc = tid + 256 * j;             // 0..767
    int d = oc >> 3, part = oc & 7;
    u16x8 o;
    #pragma unroll
    for (int e = 0; e < 8; ++e) o[e] = T[part * 8 + e][d];
    *reinterpret_cast<u16x8*>(dst + (size_t)d * 4096 + part * 8) = o;
  }
}

// ---------------- flash attention: 8 waves, in-block key-split + combine, XCD-grouped ----------------
// grid 512, XCD remap: x=blk&7, j=blk>>3 -> bh = x + 8*(j>>4), qt = j&15.
// All 16 qt-blocks of a bh (and 4 bh's) land on one XCD -> K/V stream its L2 once.
__launch_bounds__(512, 4)
__global__ void flash6(const u16* __restrict__ Qp, const u16* __restrict__ Kb,
                       const u16* __restrict__ Vtg, u16* __restrict__ aout) {
  const int blk = blockIdx.x;
  const int xcd = blk & 7, j = blk >> 3;
  const int bh = xcd + 8 * (j >> 4), qt = j & 15;
  const int b = bh >> 3, h = bh & 7;
  __shared__ __align__(16) u16 Sh[32768];
  const int tid = threadIdx.x, w = tid >> 6, lane = tid & 63;
  const int sq = w >> 2, wq = w & 3;
  const int c = lane & 15, g = lane >> 4;
  const int kbase = sq * 12288;
  const int vbase = 6144 + sq * 12288;
  const u16* qb = Qp + ((size_t)(b * 1024 + qt * 64 + wq * 16 + c)) * 768 + h * 96;
  bf16x8 qf[3];
  #pragma unroll
  for (int kc = 0; kc < 3; ++kc)
    qf[kc] = *reinterpret_cast<const bf16x8*>(qb + kc * 32 + g * 8);
  int koff[3], voff[3], loff[3];
  #pragma unroll
  for (int j2 = 0; j2 < 3; ++j2) {
    int p = wq * 192 + j2 * 64 + lane;  // 0..767
    int r = p / 12, ch = p - r * 12;
    koff[j2] = r * 768 + ch * 8;
    int d = p >> 3, vch = p & 7;
    voff[j2] = d * 4096 + ((vch ^ (d & 7)) * 8);
    loff[j2] = (wq * 192 + j2 * 64) * 8;
  }
  const u16* kb0 = Kb + ((size_t)(b * 4096 + sq * 2048)) * 768 + h * 96;
  const u16* vb0 = Vtg + ((size_t)(bh * 96)) * 4096 + sq * 2048;
  float m = -1e30f, l = 0.f;
  f32x4 acc[6] = {};
  const int sw = (c & 7) << 3;
  const int psw = (c & 7) << 1;
  const int pbase = 24576 + w * 1024 + c * 64;
  for (int kt = 0; kt < 32; ++kt) {
    __syncthreads();
    #pragma unroll
    for (int j2 = 0; j2 < 3; ++j2) gld16(kb0 + (size_t)kt * 49152 + koff[j2], &Sh[kbase + loff[j2]]);
    #pragma unroll
    for (int j2 = 0; j2 < 3; ++j2) gld16(vb0 + kt * 64 + voff[j2], &Sh[vbase + loff[j2]]);
    __syncthreads();
    f32x4 st[4] = {};
    #pragma unroll
    for (int kc = 0; kc < 3; ++kc)
      #pragma unroll
      for (int kt4 = 0; kt4 < 4; ++kt4) {
        bf16x8 kf = *reinterpret_cast<const bf16x8*>(&Sh[kbase + (kt4 * 16 + c) * 96 + kc * 32 + g * 8]);
        st[kt4] = MFMA16(kf, qf[kc], st[kt4]);
      }
    float pmax = st[0][0];
    #pragma unroll
    for (int kt4 = 0; kt4 < 4; ++kt4)
      #pragma unroll
      for (int i = 0; i < 4; ++i)
        pmax = fmaxf(pmax, st[kt4][i]);
    pmax = fmaxf(pmax, __shfl_xor(pmax, 16));
    pmax = fmaxf(pmax, __shfl_xor(pmax, 32));
    if (__any(pmax > m + 8.0f)) {
      float mn = fmaxf(m, pmax);
      float esc = exp2f(m - mn);
      m = mn;
      l *= esc;
      float er[4];
      #pragma unroll
      for (int i = 0; i < 4; ++i) er[i] = __shfl(esc, g * 4 + i);
      #pragma unroll
      for (int dc = 0; dc < 6; ++dc)
        #pragma unroll
        for (int i = 0; i < 4; ++i)
          acc[dc][i] *= er[i];
    }
    float ps = 0.f;
    #pragma unroll
    for (int kt4 = 0; kt4 < 4; ++kt4)
      #pragma unroll
      for (int i = 0; i < 4; ++i) {
        float p = exp2f(st[kt4][i] - m);
        st[kt4][i] = p;
        ps += p;
      }
    ps += __shfl_xor(ps, 16);
    ps += __shfl_xor(ps, 32);
    l += ps;
    #pragma unroll
    for (int kt4 = 0; kt4 < 4; ++kt4) {
      unsigned int u0, u1;
      asm("v_cvt_pk_bf16_f32 %0, %1, %2" : "=v"(u0) : "v"(st[kt4][0]), "v"(st[kt4][1]));
      asm("v_cvt_pk_bf16_f32 %0, %1, %2" : "=v"(u1) : "v"(st[kt4][2]), "v"(st[kt4][3]));
      const int chunk = (kt4 * 4 + g) ^ psw;
      *reinterpret_cast<uint2*>(&Sh[pbase + chunk * 4]) = make_uint2(u0, u1);
    }
    asm volatile("s_waitcnt lgkmcnt(0)" ::: "memory");
    #pragma unroll
    for (int kh = 0; kh < 2; ++kh) {
      const int rchunk = (kh * 8 + g * 2) ^ psw;
      bf16x8 pf = *reinterpret_cast<const bf16x8*>(&Sh[pbase + rchunk * 4]);
      #pragma unroll
      for (int dc = 0; dc < 6; ++dc) {
        bf16x8 vf = *reinterpret_cast<const bf16x8*>(&Sh[vbase + (dc * 16 + c) * 64 + ((kh * 32 + g * 8) ^ sw)]);
        acc[dc] = MFMA16(pf, vf, acc[dc]);
      }
    }
  }
  // ---- in-block combine of the two key-halves ----
  __syncthreads();
  float* Cb = (float*)&Sh[0];            // [4][16][96] f32 (overlays K0/V0)
  float* Ml = (float*)&Sh[24576];        // [4][16][2] f32 (overlays Pl)
  if (sq == 1) {
    #pragma unroll
    for (int dc = 0; dc < 6; ++dc)
      #pragma unroll
      for (int i = 0; i < 4; ++i)
        Cb[(wq * 16 + g * 4 + i) * 96 + dc * 16 + c] = acc[dc][i];
    if (lane < 16) {
      Ml[(wq * 16 + lane) * 2]     = m;
      Ml[(wq * 16 + lane) * 2 + 1] = l;
    }
  }
  __syncthreads();
  if (sq == 0) {
    u16* ob = aout + (size_t)(b * 1024 + qt * 64 + wq * 16) * 768 + h * 96;
    #pragma unroll
    for (int i = 0; i < 4; ++i) {
      const int q = g * 4 + i;
      float m0q = __shfl(m, q), l0q = __shfl(l, q);
      float m1q = Ml[(wq * 16 + q) * 2], l1q = Ml[(wq * 16 + q) * 2 + 1];
      float M = fmaxf(m0q, m1q);
      float e0 = exp2f(m0q - M), e1 = exp2f(m1q - M);
      float inv = 1.f / (l0q * e0 + l1q * e1);
      #pragma unroll
      for (int dc = 0; dc < 6; ++dc) {
        float a1 = Cb[(wq * 16 + q) * 96 + dc * 16 + c];
        ob[(size_t)q * 768 + dc * 16 + c] = f2bf((acc[dc][i] * e0 + a1 * e1) * inv);
      }
    }
  }
}

extern "C" void kernel_launch(void* const* d_in, const int* in_sizes, int n_in,
                              void* d_out, int out_size, void* d_ws, size_t ws_size,
                              hipStream_t stream) {
  const float* hs     = (const float*)d_in[0];
  const float* qkv_w  = (const float*)d_in[1];
  const float* qkv_b  = (const float*)d_in[2];
  const float* proj_w = (const float*)d_in[3];
  const float* proj_b = (const float*)d_in[4];
  float* out = (float*)d_out;

  u16* hs_bf  = (u16*)d_ws;                 // 6291456 u16
  u16* qkvwT  = hs_bf  + 6291456;           // 884736
  u16* projwT = qkvwT  + 884736;            // 589824
  u16* qfull  = projwT + 589824;            // 12582912 (unused by gemm now) -> vT
  u16* kbuf   = qfull  + 12582912;          // 12582912
  u16* vbuf   = kbuf   + 12582912;          // 12582912
  u16* qpol   = vbuf   + 12582912;          // 3145728
  u16* aout   = qpol   + 3145728;           // 3145728

  u16* vT     = qfull;                      // 32*96*4096 = 12582912 u16, exact fit

  prep<<<6504, 256, 0, stream>>>(hs, hs_bf, qkv_w, qkvwT, proj_w, projwT);

  gemm_bt<0><<<2304, 256, 0, stream>>>(hs_bf, qkvwT, qkv_b,
                                       qpol, kbuf, vbuf, nullptr, 384, 18, 288);
  vtrans<<<2048, 256, 0, stream>>>(vbuf, vT);
  flash6<<<512, 512, 0, stream>>>(qpol, kbuf, vT, aout);
  gemm_bt<1><<<192, 256, 0, stream>>>(aout, projwT, proj_b,
                                      nullptr, nullptr, nullptr, out, 768, 6, 24);
}

// Round 10
// 166.932 us; speedup vs baseline: 1.1916x; 1.1182x over previous
//
#include <hip/hip_runtime.h>
#include <hip/hip_bf16.h>

typedef unsigned short u16;
typedef __attribute__((ext_vector_type(8))) short bf16x8;
typedef __attribute__((ext_vector_type(8))) unsigned short u16x8;
typedef __attribute__((ext_vector_type(4))) float f32x4;

#define MFMA16(a,b,c) __builtin_amdgcn_mfma_f32_16x16x32_bf16(a,b,c,0,0,0)

__device__ __forceinline__ u16 f2bf(float f) {
  union { float f; unsigned int u; } v; v.f = f;
  unsigned int r = v.u + 0x7fffu + ((v.u >> 16) & 1u);  // RNE, finite inputs
  return (u16)(r >> 16);
}
__device__ __forceinline__ float bf2f(u16 u) {
  union { unsigned int i; float f; } v; v.i = ((unsigned int)u) << 16; return v.f;
}

__device__ __forceinline__ void gld16(const void* g, void* l) {
  __builtin_amdgcn_global_load_lds((const __attribute__((address_space(1))) void*)g,
                                   (__attribute__((address_space(3))) void*)l, 16, 0, 0);
}

// ---------------- fused prep: cast4 (blocks 0..6143) + ttrans qkv + ttrans proj ----------------
__device__ __forceinline__ void ttrans_body(const float* __restrict__ in, u16* __restrict__ out,
                                            int K, int N, int blk, int tid, u16 T[64][65]) {
  const int ntx = N >> 6;
  const int tx = blk % ntx, ty = blk / ntx;
  const int n0 = tx * 64, k0 = ty * 64;
  #pragma unroll
  for (int p = 0; p < 4; ++p) {
    int idx = p * 256 + tid;            // 0..1023
    int r = idx >> 4, ch = idx & 15;
    float4 v = *reinterpret_cast<const float4*>(in + (size_t)(k0 + r) * N + n0 + ch * 4);
    T[r][ch * 4 + 0] = f2bf(v.x);
    T[r][ch * 4 + 1] = f2bf(v.y);
    T[r][ch * 4 + 2] = f2bf(v.z);
    T[r][ch * 4 + 3] = f2bf(v.w);
  }
  __syncthreads();
  #pragma unroll
  for (int p = 0; p < 2; ++p) {
    int idx = p * 256 + tid;            // 0..511
    int rr = idx >> 3, ch = idx & 7;
    u16x8 o;
    #pragma unroll
    for (int e = 0; e < 8; ++e) o[e] = T[ch * 8 + e][rr];
    *reinterpret_cast<u16x8*>(out + (size_t)(n0 + rr) * K + k0 + ch * 8) = o;
  }
}

__global__ void prep(const float* __restrict__ hs, u16* __restrict__ hs_bf,
                     const float* __restrict__ qkv_w, u16* __restrict__ qkvwT,
                     const float* __restrict__ proj_w, u16* __restrict__ projwT) {
  __shared__ u16 T[64][65];
  const int blk = blockIdx.x, tid = threadIdx.x;
  if (blk < 6144) {
    int i = blk * 256 + tid;            // n4 = 1572864 = 6144*256 exact
    float4 v = reinterpret_cast<const float4*>(hs)[i];
    ushort4 o; o.x = f2bf(v.x); o.y = f2bf(v.y); o.z = f2bf(v.z); o.w = f2bf(v.w);
    reinterpret_cast<ushort4*>(hs_bf)[i] = o;
  } else if (blk < 6360) {
    ttrans_body(qkv_w, qkvwT, 384, 2304, blk - 6144, tid, T);
  } else {
    ttrans_body(proj_w, projwT, 768, 768, blk - 6360, tid, T);
  }
}

// ---------------- GEMM: C[M,N] = A[M,K] * Bt[N,K]^T + bias ----------------
// 128x128 tile, BK=32, dbuf LDS (single 32KB arena), counted-vmcnt prefetch, XCD swizzle.
// EPI 0 (qkv): q cols (bcol<768) -> fused 2x2 maxpool*SC -> qp (bf16);
//              k cols -> kbuf natural; v cols (bcol>=1536) -> in-LDS transpose -> vT.
// EPI 1: fp32 out (proj).
template<int EPI>
__launch_bounds__(256)
__global__ void gemm_bt(const u16* __restrict__ A, const u16* __restrict__ Bt,
                        const float* __restrict__ bias,
                        u16* __restrict__ qp, u16* __restrict__ ok, u16* __restrict__ ov,
                        float* __restrict__ of, int K, int nbx, int cpx) {
  __shared__ __align__(16) u16 Sh[16384];   // As = Sh[0..8191], Bs = Sh[8192..16383]
  const int id = blockIdx.x;
  const int id2 = (id & 7) * cpx + (id >> 3);   // cpx = nwg/8
  const int bx = id2 % nbx, by = id2 / nbx;
  const int tid = threadIdx.x;
  const int wave = tid >> 6, lane = tid & 63;
  const int c = lane & 15, g = lane >> 4;
  const int brow = by * 128, bcol = bx * 128;
  const int wr = (wave >> 1) * 64, wc = (wave & 1) * 64;
  f32x4 acc[4][4] = {};
  const int srow = wave * 32 + (lane >> 2);
  const int scol = (lane & 3) * 8;
  const u16* agp0 = A  + (size_t)(brow + srow) * K + scol;
  const u16* agp1 = A  + (size_t)(brow + srow + 16) * K + scol;
  const u16* bgp0 = Bt + (size_t)(bcol + srow) * K + scol;
  const u16* bgp1 = Bt + (size_t)(bcol + srow + 16) * K + scol;
  const int lo0 = wave * 1024, lo1 = wave * 1024 + 512;
  const int nk = K >> 5;
  gld16(agp0, &Sh[lo0]);
  gld16(agp1, &Sh[lo1]);
  gld16(bgp0, &Sh[8192 + lo0]);
  gld16(bgp1, &Sh[8192 + lo1]);
  for (int ks = 0; ks < nk; ++ks) {
    const int cur = ks & 1;
    if (ks + 1 < nk) {
      const int k1 = (ks + 1) << 5;
      const int nb = (cur ^ 1) * 4096;
      gld16(agp0 + k1, &Sh[nb + lo0]);
      gld16(agp1 + k1, &Sh[nb + lo1]);
      gld16(bgp0 + k1, &Sh[8192 + nb + lo0]);
      gld16(bgp1 + k1, &Sh[8192 + nb + lo1]);
      asm volatile("s_waitcnt vmcnt(4)" ::: "memory");
    } else {
      asm volatile("s_waitcnt vmcnt(0)" ::: "memory");
    }
    __builtin_amdgcn_s_barrier();
    __builtin_amdgcn_sched_barrier(0);
    const int cb = cur * 4096;
    bf16x8 af[4], bfr[4];
    #pragma unroll
    for (int mi = 0; mi < 4; ++mi)
      af[mi] = *reinterpret_cast<const bf16x8*>(&Sh[cb + (wr + mi * 16 + c) * 32 + g * 8]);
    #pragma unroll
    for (int ni = 0; ni < 4; ++ni)
      bfr[ni] = *reinterpret_cast<const bf16x8*>(&Sh[8192 + cb + (wc + ni * 16 + c) * 32 + g * 8]);
    #pragma unroll
    for (int mi = 0; mi < 4; ++mi)
      #pragma unroll
      for (int ni = 0; ni < 4; ++ni)
        acc[mi][ni] = MFMA16(af[mi], bfr[ni], acc[mi][ni]);
    __builtin_amdgcn_sched_barrier(0);
    __builtin_amdgcn_s_barrier();
  }
  if (EPI == 0 && bcol < 768) {
    // ---- fused 2x2 maxpool: block = rows (h0,h0+1) x all w; pooled rows hq*32+wq ----
    const float SC = 0.14724744f;       // 96^-0.5 * log2(e)
    float* P = (float*)&Sh[0];          // [2][32][64] f32 = 16KB
    float m01[4][4], m23[4][4];
    #pragma unroll
    for (int mi = 0; mi < 4; ++mi)
      #pragma unroll
      for (int ni = 0; ni < 4; ++ni) {
        m01[mi][ni] = fmaxf(acc[mi][ni][0], acc[mi][ni][1]);
        m23[mi][ni] = fmaxf(acc[mi][ni][2], acc[mi][ni][3]);
      }
    if (wr == 64) {                     // h0+1 half: publish partials
      #pragma unroll
      for (int mi = 0; mi < 4; ++mi)
        #pragma unroll
        for (int ni = 0; ni < 4; ++ni) {
          const int pw = mi * 8 + g * 2;
          P[(wave & 1) * 2048 + pw * 64 + ni * 16 + c]       = m01[mi][ni];
          P[(wave & 1) * 2048 + (pw + 1) * 64 + ni * 16 + c] = m23[mi][ni];
        }
    }
    __syncthreads();
    if (wr == 0) {                      // h0 half: combine + write qpol
      const int b = brow >> 12;
      const int hq = (brow >> 7) & 31;
      const size_t rbase = (size_t)(b * 1024 + hq * 32);
      #pragma unroll
      for (int mi = 0; mi < 4; ++mi)
        #pragma unroll
        for (int ni = 0; ni < 4; ++ni) {
          const int col = bcol + wc + ni * 16 + c;
          const float bz = bias[col];
          const int pw = mi * 8 + g * 2;
          float v0 = fmaxf(m01[mi][ni], P[(wave & 1) * 2048 + pw * 64 + ni * 16 + c]);
          float v1 = fmaxf(m23[mi][ni], P[(wave & 1) * 2048 + (pw + 1) * 64 + ni * 16 + c]);
          qp[(rbase + pw) * 768 + col]     = f2bf((v0 + bz) * SC);
          qp[(rbase + pw + 1) * 768 + col] = f2bf((v1 + bz) * SC);
        }
    }
    return;
  }
  if (EPI == 0 && bcol >= 1536) {
    // ---- V epilogue: in-LDS transpose -> vT[(b*768 + vc0 + j)*4096 + s0 + s] ----
    // T[j][s] 128x128 u16, chunk-swizzled: u16 addr = j*128 + (s ^ ((j&15)<<2))
    u16* T = &Sh[0];
    const int vc0 = bcol - 1536;
    const int bq = brow >> 12;
    const int s0 = brow & 4095;
    #pragma unroll
    for (int ni = 0; ni < 4; ++ni) {
      const int j = wc + ni * 16 + c;
      const float bz = bias[bcol + j];
      const int key = (j & 15) << 2;
      #pragma unroll
      for (int mi = 0; mi < 4; ++mi) {
        const int rb = wr + mi * 16 + g * 4;
        ushort4 o;
        o.x = f2bf(acc[mi][ni][0] + bz);
        o.y = f2bf(acc[mi][ni][1] + bz);
        o.z = f2bf(acc[mi][ni][2] + bz);
        o.w = f2bf(acc[mi][ni][3] + bz);
        *reinterpret_cast<ushort4*>(&T[j * 128 + (rb ^ key)]) = o;
      }
    }
    __syncthreads();
    u16* vb2 = ov + ((size_t)(bq * 768 + vc0)) * 4096 + s0;
    #pragma unroll
    for (int p = 0; p < 8; ++p) {
      const int j = p * 16 + wave * 4 + (lane >> 4);
      const int sc = lane & 15;
      const int key = j & 15;
      uint2 lo = *reinterpret_cast<uint2*>(&T[j * 128 + ((sc ^ key) << 2)]);
      uint2 hi = *reinterpret_cast<uint2*>(&T[j * 128 + (((sc + 16) ^ key) << 2)]);
      *reinterpret_cast<uint2*>(vb2 + (size_t)j * 4096 + sc * 4)      = lo;
      *reinterpret_cast<uint2*>(vb2 + (size_t)j * 4096 + 64 + sc * 4) = hi;
    }
    return;
  }
  #pragma unroll
  for (int mi = 0; mi < 4; ++mi) {
    #pragma unroll
    for (int ni = 0; ni < 4; ++ni) {
      const int col = bcol + wc + ni * 16 + c;
      const float bz = bias[col];
      #pragma unroll
      for (int i = 0; i < 4; ++i) {
        const int row = brow + wr + mi * 16 + g * 4 + i;
        float v = acc[mi][ni][i] + bz;
        if (EPI == 0) {
          ok[(size_t)row * 768 + col - 768] = f2bf(v);
        } else {
          of[(size_t)row * 768 + col] = v;
        }
      }
    }
  }
}

// ---------------- flash attention: 8 waves, in-block key-split + combine, XCD-grouped ----------------
// grid 512, XCD remap: x=blk&7, j=blk>>3 -> bh = x + 8*(j>>4), qt = j&15.
__launch_bounds__(512, 4)
__global__ void flash6(const u16* __restrict__ Qp, const u16* __restrict__ Kb,
                       const u16* __restrict__ Vtg, u16* __restrict__ aout) {
  const int blk = blockIdx.x;
  const int xcd = blk & 7, j = blk >> 3;
  const int bh = xcd + 8 * (j >> 4), qt = j & 15;
  const int b = bh >> 3, h = bh & 7;
  __shared__ __align__(16) u16 Sh[32768];
  const int tid = threadIdx.x, w = tid >> 6, lane = tid & 63;
  const int sq = w >> 2, wq = w & 3;
  const int c = lane & 15, g = lane >> 4;
  const int kbase = sq * 12288;
  const int vbase = 6144 + sq * 12288;
  const u16* qb = Qp + ((size_t)(b * 1024 + qt * 64 + wq * 16 + c)) * 768 + h * 96;
  bf16x8 qf[3];
  #pragma unroll
  for (int kc = 0; kc < 3; ++kc)
    qf[kc] = *reinterpret_cast<const bf16x8*>(qb + kc * 32 + g * 8);
  int koff[3], voff[3], loff[3];
  #pragma unroll
  for (int j2 = 0; j2 < 3; ++j2) {
    int p = wq * 192 + j2 * 64 + lane;  // 0..767
    int r = p / 12, ch = p - r * 12;
    koff[j2] = r * 768 + ch * 8;
    int d = p >> 3, vch = p & 7;
    voff[j2] = d * 4096 + ((vch ^ (d & 7)) * 8);
    loff[j2] = (wq * 192 + j2 * 64) * 8;
  }
  const u16* kb0 = Kb + ((size_t)(b * 4096 + sq * 2048)) * 768 + h * 96;
  const u16* vb0 = Vtg + ((size_t)(bh * 96)) * 4096 + sq * 2048;
  float m = -1e30f, l = 0.f;
  f32x4 acc[6] = {};
  const int sw = (c & 7) << 3;
  const int psw = (c & 7) << 1;
  const int pbase = 24576 + w * 1024 + c * 64;
  for (int kt = 0; kt < 32; ++kt) {
    __syncthreads();
    #pragma unroll
    for (int j2 = 0; j2 < 3; ++j2) gld16(kb0 + (size_t)kt * 49152 + koff[j2], &Sh[kbase + loff[j2]]);
    #pragma unroll
    for (int j2 = 0; j2 < 3; ++j2) gld16(vb0 + kt * 64 + voff[j2], &Sh[vbase + loff[j2]]);
    __syncthreads();
    f32x4 st[4] = {};
    #pragma unroll
    for (int kc = 0; kc < 3; ++kc)
      #pragma unroll
      for (int kt4 = 0; kt4 < 4; ++kt4) {
        bf16x8 kf = *reinterpret_cast<const bf16x8*>(&Sh[kbase + (kt4 * 16 + c) * 96 + kc * 32 + g * 8]);
        st[kt4] = MFMA16(kf, qf[kc], st[kt4]);
      }
    float pmax = st[0][0];
    #pragma unroll
    for (int kt4 = 0; kt4 < 4; ++kt4)
      #pragma unroll
      for (int i = 0; i < 4; ++i)
        pmax = fmaxf(pmax, st[kt4][i]);
    pmax = fmaxf(pmax, __shfl_xor(pmax, 16));
    pmax = fmaxf(pmax, __shfl_xor(pmax, 32));
    if (__any(pmax > m + 8.0f)) {
      float mn = fmaxf(m, pmax);
      float esc = exp2f(m - mn);
      m = mn;
      l *= esc;
      float er[4];
      #pragma unroll
      for (int i = 0; i < 4; ++i) er[i] = __shfl(esc, g * 4 + i);
      #pragma unroll
      for (int dc = 0; dc < 6; ++dc)
        #pragma unroll
        for (int i = 0; i < 4; ++i)
          acc[dc][i] *= er[i];
    }
    float ps = 0.f;
    #pragma unroll
    for (int kt4 = 0; kt4 < 4; ++kt4)
      #pragma unroll
      for (int i = 0; i < 4; ++i) {
        float p = exp2f(st[kt4][i] - m);
        st[kt4][i] = p;
        ps += p;
      }
    ps += __shfl_xor(ps, 16);
    ps += __shfl_xor(ps, 32);
    l += ps;
    #pragma unroll
    for (int kt4 = 0; kt4 < 4; ++kt4) {
      unsigned int u0, u1;
      asm("v_cvt_pk_bf16_f32 %0, %1, %2" : "=v"(u0) : "v"(st[kt4][0]), "v"(st[kt4][1]));
      asm("v_cvt_pk_bf16_f32 %0, %1, %2" : "=v"(u1) : "v"(st[kt4][2]), "v"(st[kt4][3]));
      const int chunk = (kt4 * 4 + g) ^ psw;
      *reinterpret_cast<uint2*>(&Sh[pbase + chunk * 4]) = make_uint2(u0, u1);
    }
    asm volatile("s_waitcnt lgkmcnt(0)" ::: "memory");
    #pragma unroll
    for (int kh = 0; kh < 2; ++kh) {
      const int rchunk = (kh * 8 + g * 2) ^ psw;
      bf16x8 pf = *reinterpret_cast<const bf16x8*>(&Sh[pbase + rchunk * 4]);
      #pragma unroll
      for (int dc = 0; dc < 6; ++dc) {
        bf16x8 vf = *reinterpret_cast<const bf16x8*>(&Sh[vbase + (dc * 16 + c) * 64 + ((kh * 32 + g * 8) ^ sw)]);
        acc[dc] = MFMA16(pf, vf, acc[dc]);
      }
    }
  }
  // ---- in-block combine of the two key-halves ----
  __syncthreads();
  float* Cb = (float*)&Sh[0];            // [4][16][96] f32 (overlays K0/V0)
  float* Ml = (float*)&Sh[24576];        // [4][16][2] f32 (overlays Pl)
  if (sq == 1) {
    #pragma unroll
    for (int dc = 0; dc < 6; ++dc)
      #pragma unroll
      for (int i = 0; i < 4; ++i)
        Cb[(wq * 16 + g * 4 + i) * 96 + dc * 16 + c] = acc[dc][i];
    if (lane < 16) {
      Ml[(wq * 16 + lane) * 2]     = m;
      Ml[(wq * 16 + lane) * 2 + 1] = l;
    }
  }
  __syncthreads();
  if (sq == 0) {
    u16* ob = aout + (size_t)(b * 1024 + qt * 64 + wq * 16) * 768 + h * 96;
    #pragma unroll
    for (int i = 0; i < 4; ++i) {
      const int q = g * 4 + i;
      float m0q = __shfl(m, q), l0q = __shfl(l, q);
      float m1q = Ml[(wq * 16 + q) * 2], l1q = Ml[(wq * 16 + q) * 2 + 1];
      float M = fmaxf(m0q, m1q);
      float e0 = exp2f(m0q - M), e1 = exp2f(m1q - M);
      float inv = 1.f / (l0q * e0 + l1q * e1);
      #pragma unroll
      for (int dc = 0; dc < 6; ++dc) {
        float a1 = Cb[(wq * 16 + q) * 96 + dc * 16 + c];
        ob[(size_t)q * 768 + dc * 16 + c] = f2bf((acc[dc][i] * e0 + a1 * e1) * inv);
      }
    }
  }
}

extern "C" void kernel_launch(void* const* d_in, const int* in_sizes, int n_in,
                              void* d_out, int out_size, void* d_ws, size_t ws_size,
                              hipStream_t stream) {
  const float* hs     = (const float*)d_in[0];
  const float* qkv_w  = (const float*)d_in[1];
  const float* qkv_b  = (const float*)d_in[2];
  const float* proj_w = (const float*)d_in[3];
  const float* proj_b = (const float*)d_in[4];
  float* out = (float*)d_out;

  u16* hs_bf  = (u16*)d_ws;                 // 6291456 u16
  u16* qkvwT  = hs_bf  + 6291456;           // 884736
  u16* projwT = qkvwT  + 884736;            // 589824
  u16* vT     = projwT + 589824;            // 12582912 (32*96*4096)
  u16* kbuf   = vT     + 12582912;          // 12582912
  u16* spare  = kbuf   + 12582912;          // 12582912 (unused)
  u16* qpol   = spare  + 12582912;          // 3145728
  u16* aout   = qpol   + 3145728;           // 3145728

  prep<<<6504, 256, 0, stream>>>(hs, hs_bf, qkv_w, qkvwT, proj_w, projwT);

  gemm_bt<0><<<2304, 256, 0, stream>>>(hs_bf, qkvwT, qkv_b,
                                       qpol, kbuf, vT, nullptr, 384, 18, 288);
  flash6<<<512, 512, 0, stream>>>(qpol, kbuf, vT, aout);
  gemm_bt<1><<<192, 256, 0, stream>>>(aout, projwT, proj_b,
                                      nullptr, nullptr, nullptr, out, 768, 6, 24);
}

// Round 11
// 160.572 us; speedup vs baseline: 1.2388x; 1.0396x over previous
//
#include <hip/hip_runtime.h>
#include <hip/hip_bf16.h>

typedef unsigned short u16;
typedef __attribute__((ext_vector_type(8))) short bf16x8;
typedef __attribute__((ext_vector_type(8))) unsigned short u16x8;
typedef __attribute__((ext_vector_type(4))) float f32x4;

#define MFMA16(a,b,c) __builtin_amdgcn_mfma_f32_16x16x32_bf16(a,b,c,0,0,0)

__device__ __forceinline__ u16 f2bf(float f) {
  union { float f; unsigned int u; } v; v.f = f;
  unsigned int r = v.u + 0x7fffu + ((v.u >> 16) & 1u);  // RNE, finite inputs
  return (u16)(r >> 16);
}
__device__ __forceinline__ float bf2f(u16 u) {
  union { unsigned int i; float f; } v; v.i = ((unsigned int)u) << 16; return v.f;
}

__device__ __forceinline__ void gld16(const void* g, void* l) {
  __builtin_amdgcn_global_load_lds((const __attribute__((address_space(1))) void*)g,
                                   (__attribute__((address_space(3))) void*)l, 16, 0, 0);
}

// ---------------- fused prep: cast4 (blocks 0..6143) + ttrans qkv + ttrans proj ----------------
__device__ __forceinline__ void ttrans_body(const float* __restrict__ in, u16* __restrict__ out,
                                            int K, int N, int blk, int tid, u16 T[64][65]) {
  const int ntx = N >> 6;
  const int tx = blk % ntx, ty = blk / ntx;
  const int n0 = tx * 64, k0 = ty * 64;
  #pragma unroll
  for (int p = 0; p < 4; ++p) {
    int idx = p * 256 + tid;            // 0..1023
    int r = idx >> 4, ch = idx & 15;
    float4 v = *reinterpret_cast<const float4*>(in + (size_t)(k0 + r) * N + n0 + ch * 4);
    T[r][ch * 4 + 0] = f2bf(v.x);
    T[r][ch * 4 + 1] = f2bf(v.y);
    T[r][ch * 4 + 2] = f2bf(v.z);
    T[r][ch * 4 + 3] = f2bf(v.w);
  }
  __syncthreads();
  #pragma unroll
  for (int p = 0; p < 2; ++p) {
    int idx = p * 256 + tid;            // 0..511
    int rr = idx >> 3, ch = idx & 7;
    u16x8 o;
    #pragma unroll
    for (int e = 0; e < 8; ++e) o[e] = T[ch * 8 + e][rr];
    *reinterpret_cast<u16x8*>(out + (size_t)(n0 + rr) * K + k0 + ch * 8) = o;
  }
}

__global__ void prep(const float* __restrict__ hs, u16* __restrict__ hs_bf,
                     const float* __restrict__ qkv_w, u16* __restrict__ qkvwT,
                     const float* __restrict__ proj_w, u16* __restrict__ projwT) {
  __shared__ u16 T[64][65];
  const int blk = blockIdx.x, tid = threadIdx.x;
  if (blk < 6144) {
    int i = blk * 256 + tid;            // n4 = 1572864 = 6144*256 exact
    float4 v = reinterpret_cast<const float4*>(hs)[i];
    ushort4 o; o.x = f2bf(v.x); o.y = f2bf(v.y); o.z = f2bf(v.z); o.w = f2bf(v.w);
    reinterpret_cast<ushort4*>(hs_bf)[i] = o;
  } else if (blk < 6360) {
    ttrans_body(qkv_w, qkvwT, 384, 2304, blk - 6144, tid, T);
  } else {
    ttrans_body(proj_w, projwT, 768, 768, blk - 6360, tid, T);
  }
}

// ---------------- GEMM: C[M,N] = A[M,K] * Bt[N,K]^T + bias ----------------
// 128x128 tile, BK=32, dbuf LDS (single 32KB arena), counted-vmcnt prefetch, XCD swizzle.
// EPI 0 (qkv): q cols (bcol<768) -> fused 2x2 maxpool*SC -> qp (bf16);
//              k cols -> kbuf natural; v cols (bcol>=1536) -> in-LDS transpose -> vT
//              with per-64-key-tile column permutation pi (zero-transport PV in flash).
// EPI 1: fp32 out (proj).
template<int EPI>
__launch_bounds__(256)
__global__ void gemm_bt(const u16* __restrict__ A, const u16* __restrict__ Bt,
                        const float* __restrict__ bias,
                        u16* __restrict__ qp, u16* __restrict__ ok, u16* __restrict__ ov,
                        float* __restrict__ of, int K, int nbx, int cpx) {
  __shared__ __align__(16) u16 Sh[16384];   // As = Sh[0..8191], Bs = Sh[8192..16383]
  const int id = blockIdx.x;
  const int id2 = (id & 7) * cpx + (id >> 3);   // cpx = nwg/8
  const int bx = id2 % nbx, by = id2 / nbx;
  const int tid = threadIdx.x;
  const int wave = tid >> 6, lane = tid & 63;
  const int c = lane & 15, g = lane >> 4;
  const int brow = by * 128, bcol = bx * 128;
  const int wr = (wave >> 1) * 64, wc = (wave & 1) * 64;
  f32x4 acc[4][4] = {};
  const int srow = wave * 32 + (lane >> 2);
  const int scol = (lane & 3) * 8;
  const u16* agp0 = A  + (size_t)(brow + srow) * K + scol;
  const u16* agp1 = A  + (size_t)(brow + srow + 16) * K + scol;
  const u16* bgp0 = Bt + (size_t)(bcol + srow) * K + scol;
  const u16* bgp1 = Bt + (size_t)(bcol + srow + 16) * K + scol;
  const int lo0 = wave * 1024, lo1 = wave * 1024 + 512;
  const int nk = K >> 5;
  gld16(agp0, &Sh[lo0]);
  gld16(agp1, &Sh[lo1]);
  gld16(bgp0, &Sh[8192 + lo0]);
  gld16(bgp1, &Sh[8192 + lo1]);
  for (int ks = 0; ks < nk; ++ks) {
    const int cur = ks & 1;
    if (ks + 1 < nk) {
      const int k1 = (ks + 1) << 5;
      const int nb = (cur ^ 1) * 4096;
      gld16(agp0 + k1, &Sh[nb + lo0]);
      gld16(agp1 + k1, &Sh[nb + lo1]);
      gld16(bgp0 + k1, &Sh[8192 + nb + lo0]);
      gld16(bgp1 + k1, &Sh[8192 + nb + lo1]);
      asm volatile("s_waitcnt vmcnt(4)" ::: "memory");
    } else {
      asm volatile("s_waitcnt vmcnt(0)" ::: "memory");
    }
    __builtin_amdgcn_s_barrier();
    __builtin_amdgcn_sched_barrier(0);
    const int cb = cur * 4096;
    bf16x8 af[4], bfr[4];
    #pragma unroll
    for (int mi = 0; mi < 4; ++mi)
      af[mi] = *reinterpret_cast<const bf16x8*>(&Sh[cb + (wr + mi * 16 + c) * 32 + g * 8]);
    #pragma unroll
    for (int ni = 0; ni < 4; ++ni)
      bfr[ni] = *reinterpret_cast<const bf16x8*>(&Sh[8192 + cb + (wc + ni * 16 + c) * 32 + g * 8]);
    #pragma unroll
    for (int mi = 0; mi < 4; ++mi)
      #pragma unroll
      for (int ni = 0; ni < 4; ++ni)
        acc[mi][ni] = MFMA16(af[mi], bfr[ni], acc[mi][ni]);
    __builtin_amdgcn_sched_barrier(0);
    __builtin_amdgcn_s_barrier();
  }
  if (EPI == 0 && bcol < 768) {
    // ---- fused 2x2 maxpool: block = rows (h0,h0+1) x all w; pooled rows hq*32+wq ----
    const float SC = 0.14724744f;       // 96^-0.5 * log2(e)
    float* P = (float*)&Sh[0];          // [2][32][64] f32 = 16KB
    float m01[4][4], m23[4][4];
    #pragma unroll
    for (int mi = 0; mi < 4; ++mi)
      #pragma unroll
      for (int ni = 0; ni < 4; ++ni) {
        m01[mi][ni] = fmaxf(acc[mi][ni][0], acc[mi][ni][1]);
        m23[mi][ni] = fmaxf(acc[mi][ni][2], acc[mi][ni][3]);
      }
    if (wr == 64) {                     // h0+1 half: publish partials
      #pragma unroll
      for (int mi = 0; mi < 4; ++mi)
        #pragma unroll
        for (int ni = 0; ni < 4; ++ni) {
          const int pw = mi * 8 + g * 2;
          P[(wave & 1) * 2048 + pw * 64 + ni * 16 + c]       = m01[mi][ni];
          P[(wave & 1) * 2048 + (pw + 1) * 64 + ni * 16 + c] = m23[mi][ni];
        }
    }
    __syncthreads();
    if (wr == 0) {                      // h0 half: combine + write qpol
      const int b = brow >> 12;
      const int hq = (brow >> 7) & 31;
      const size_t rbase = (size_t)(b * 1024 + hq * 32);
      #pragma unroll
      for (int mi = 0; mi < 4; ++mi)
        #pragma unroll
        for (int ni = 0; ni < 4; ++ni) {
          const int col = bcol + wc + ni * 16 + c;
          const float bz = bias[col];
          const int pw = mi * 8 + g * 2;
          float v0 = fmaxf(m01[mi][ni], P[(wave & 1) * 2048 + pw * 64 + ni * 16 + c]);
          float v1 = fmaxf(m23[mi][ni], P[(wave & 1) * 2048 + (pw + 1) * 64 + ni * 16 + c]);
          qp[(rbase + pw) * 768 + col]     = f2bf((v0 + bz) * SC);
          qp[(rbase + pw + 1) * 768 + col] = f2bf((v1 + bz) * SC);
        }
    }
    return;
  }
  if (EPI == 0 && bcol >= 1536) {
    // ---- V epilogue: in-LDS transpose -> vT with per-64-tile key permutation ----
    // pi(32kh+8g+4u+i) = 16(2kh+u)+4g+i; 4-key word sc goes to position word p4(sc).
    u16* T = &Sh[0];
    const int vc0 = bcol - 1536;
    const int bq = brow >> 12;
    const int s0 = brow & 4095;
    #pragma unroll
    for (int ni = 0; ni < 4; ++ni) {
      const int j = wc + ni * 16 + c;
      const float bz = bias[bcol + j];
      const int key = (j & 15) << 2;
      #pragma unroll
      for (int mi = 0; mi < 4; ++mi) {
        const int rb = wr + mi * 16 + g * 4;
        ushort4 o;
        o.x = f2bf(acc[mi][ni][0] + bz);
        o.y = f2bf(acc[mi][ni][1] + bz);
        o.z = f2bf(acc[mi][ni][2] + bz);
        o.w = f2bf(acc[mi][ni][3] + bz);
        *reinterpret_cast<ushort4*>(&T[j * 128 + (rb ^ key)]) = o;
      }
    }
    __syncthreads();
    u16* vb2 = ov + ((size_t)(bq * 768 + vc0)) * 4096 + s0;
    #pragma unroll
    for (int p = 0; p < 8; ++p) {
      const int j = p * 16 + wave * 4 + (lane >> 4);
      const int sc = lane & 15;
      const int key = j & 15;
      const int p4 = 8 * (sc >> 3) + 2 * (sc & 3) + ((sc >> 2) & 1);
      uint2 lo = *reinterpret_cast<uint2*>(&T[j * 128 + ((sc ^ key) << 2)]);
      uint2 hi = *reinterpret_cast<uint2*>(&T[j * 128 + (((sc + 16) ^ key) << 2)]);
      *reinterpret_cast<uint2*>(vb2 + (size_t)j * 4096 + p4 * 4)      = lo;
      *reinterpret_cast<uint2*>(vb2 + (size_t)j * 4096 + 64 + p4 * 4) = hi;
    }
    return;
  }
  #pragma unroll
  for (int mi = 0; mi < 4; ++mi) {
    #pragma unroll
    for (int ni = 0; ni < 4; ++ni) {
      const int col = bcol + wc + ni * 16 + c;
      const float bz = bias[col];
      #pragma unroll
      for (int i = 0; i < 4; ++i) {
        const int row = brow + wr + mi * 16 + g * 4 + i;
        float v = acc[mi][ni][i] + bz;
        if (EPI == 0) {
          ok[(size_t)row * 768 + col - 768] = f2bf(v);
        } else {
          of[(size_t)row * 768 + col] = v;
        }
      }
    }
  }
}

// ---------------- flash attention: 8 waves, in-block key-split + combine, XCD-grouped ----------------
// grid 512, XCD remap: x=blk&7, j=blk>>3 -> bh = x + 8*(j>>4), qt = j&15.
// Zero-LDS P transport: V keys pre-permuted in vT so PV A-frag is in-lane cvt_pk words.
// LDS 48KB: K0@0, V0@6144, K1@12288, V1@18432 (u16 idx).
__launch_bounds__(512, 4)
__global__ void flash7(const u16* __restrict__ Qp, const u16* __restrict__ Kb,
                       const u16* __restrict__ Vtg, u16* __restrict__ aout) {
  const int blk = blockIdx.x;
  const int xcd = blk & 7, j = blk >> 3;
  const int bh = xcd + 8 * (j >> 4), qt = j & 15;
  const int b = bh >> 3, h = bh & 7;
  __shared__ __align__(16) u16 Sh[24576];
  const int tid = threadIdx.x, w = tid >> 6, lane = tid & 63;
  const int sq = w >> 2, wq = w & 3;
  const int c = lane & 15, g = lane >> 4;
  const int kbase = sq * 12288;
  const int vbase = 6144 + sq * 12288;
  const u16* qb = Qp + ((size_t)(b * 1024 + qt * 64 + wq * 16 + c)) * 768 + h * 96;
  bf16x8 qf[3];
  #pragma unroll
  for (int kc = 0; kc < 3; ++kc)
    qf[kc] = *reinterpret_cast<const bf16x8*>(qb + kc * 32 + g * 8);
  int koff[3], voff[3], loff[3];
  #pragma unroll
  for (int j2 = 0; j2 < 3; ++j2) {
    int p = wq * 192 + j2 * 64 + lane;  // 0..767
    int r = p / 12, ch = p - r * 12;
    koff[j2] = r * 768 + ch * 8;
    int d = p >> 3, vch = p & 7;
    voff[j2] = d * 4096 + ((vch ^ (d & 7)) * 8);
    loff[j2] = (wq * 192 + j2 * 64) * 8;
  }
  const u16* kb0 = Kb + ((size_t)(b * 4096 + sq * 2048)) * 768 + h * 96;
  const u16* vb0 = Vtg + ((size_t)(bh * 96)) * 4096 + sq * 2048;
  float m = -1e30f, l = 0.f;
  f32x4 acc[6] = {};
  const int sw = (c & 7) << 3;
  for (int kt = 0; kt < 32; ++kt) {
    __syncthreads();
    #pragma unroll
    for (int j2 = 0; j2 < 3; ++j2) gld16(kb0 + (size_t)kt * 49152 + koff[j2], &Sh[kbase + loff[j2]]);
    #pragma unroll
    for (int j2 = 0; j2 < 3; ++j2) gld16(vb0 + kt * 64 + voff[j2], &Sh[vbase + loff[j2]]);
    __syncthreads();
    f32x4 st[4] = {};
    #pragma unroll
    for (int kc = 0; kc < 3; ++kc)
      #pragma unroll
      for (int kt4 = 0; kt4 < 4; ++kt4) {
        bf16x8 kf = *reinterpret_cast<const bf16x8*>(&Sh[kbase + (kt4 * 16 + c) * 96 + kc * 32 + g * 8]);
        st[kt4] = MFMA16(kf, qf[kc], st[kt4]);
      }
    float pmax = st[0][0];
    #pragma unroll
    for (int kt4 = 0; kt4 < 4; ++kt4)
      #pragma unroll
      for (int i = 0; i < 4; ++i)
        pmax = fmaxf(pmax, st[kt4][i]);
    pmax = fmaxf(pmax, __shfl_xor(pmax, 16));
    pmax = fmaxf(pmax, __shfl_xor(pmax, 32));
    if (__any(pmax > m + 8.0f)) {
      float mn = fmaxf(m, pmax);
      float esc = exp2f(m - mn);
      m = mn;
      l *= esc;
      float er[4];
      #pragma unroll
      for (int i = 0; i < 4; ++i) er[i] = __shfl(esc, g * 4 + i);
      #pragma unroll
      for (int dc = 0; dc < 6; ++dc)
        #pragma unroll
        for (int i = 0; i < 4; ++i)
          acc[dc][i] *= er[i];
    }
    float ps = 0.f;
    #pragma unroll
    for (int kt4 = 0; kt4 < 4; ++kt4)
      #pragma unroll
      for (int i = 0; i < 4; ++i) {
        float p = exp2f(st[kt4][i] - m);
        st[kt4][i] = p;
        ps += p;
      }
    ps += __shfl_xor(ps, 16);
    ps += __shfl_xor(ps, 32);
    l += ps;
    // pack P in-lane: uu[t][j] = bf16 pair (st[t][2j], st[t][2j+1])
    unsigned int uu[4][2];
    #pragma unroll
    for (int kt4 = 0; kt4 < 4; ++kt4) {
      asm("v_cvt_pk_bf16_f32 %0, %1, %2" : "=v"(uu[kt4][0]) : "v"(st[kt4][0]), "v"(st[kt4][1]));
      asm("v_cvt_pk_bf16_f32 %0, %1, %2" : "=v"(uu[kt4][1]) : "v"(st[kt4][2]), "v"(st[kt4][3]));
    }
    // PV: A-frag is in-lane thanks to the vT key permutation
    #pragma unroll
    for (int kh = 0; kh < 2; ++kh) {
      union { unsigned int wrd[4]; bf16x8 v; } pfu;
      pfu.wrd[0] = uu[2 * kh][0];
      pfu.wrd[1] = uu[2 * kh][1];
      pfu.wrd[2] = uu[2 * kh + 1][0];
      pfu.wrd[3] = uu[2 * kh + 1][1];
      bf16x8 pf = pfu.v;
      #pragma unroll
      for (int dc = 0; dc < 6; ++dc) {
        bf16x8 vf = *reinterpret_cast<const bf16x8*>(&Sh[vbase + (dc * 16 + c) * 64 + ((kh * 32 + g * 8) ^ sw)]);
        acc[dc] = MFMA16(pf, vf, acc[dc]);
      }
    }
  }
  // ---- in-block combine of the two key-halves ----
  __syncthreads();
  float* Cb = (float*)&Sh[0];            // [4][16][96] f32 = 24KB (overlays K0/V0)
  float* Ml = (float*)&Sh[12288];        // [4][16][2] f32 (overlays K1)
  if (sq == 1) {
    #pragma unroll
    for (int dc = 0; dc < 6; ++dc)
      #pragma unroll
      for (int i = 0; i < 4; ++i)
        Cb[(wq * 16 + g * 4 + i) * 96 + dc * 16 + c] = acc[dc][i];
    if (lane < 16) {
      Ml[(wq * 16 + lane) * 2]     = m;
      Ml[(wq * 16 + lane) * 2 + 1] = l;
    }
  }
  __syncthreads();
  if (sq == 0) {
    u16* ob = aout + (size_t)(b * 1024 + qt * 64 + wq * 16) * 768 + h * 96;
    #pragma unroll
    for (int i = 0; i < 4; ++i) {
      const int q = g * 4 + i;
      float m0q = __shfl(m, q), l0q = __shfl(l, q);
      float m1q = Ml[(wq * 16 + q) * 2], l1q = Ml[(wq * 16 + q) * 2 + 1];
      float M = fmaxf(m0q, m1q);
      float e0 = exp2f(m0q - M), e1 = exp2f(m1q - M);
      float inv = 1.f / (l0q * e0 + l1q * e1);
      #pragma unroll
      for (int dc = 0; dc < 6; ++dc) {
        float a1 = Cb[(wq * 16 + q) * 96 + dc * 16 + c];
        ob[(size_t)q * 768 + dc * 16 + c] = f2bf((acc[dc][i] * e0 + a1 * e1) * inv);
      }
    }
  }
}

extern "C" void kernel_launch(void* const* d_in, const int* in_sizes, int n_in,
                              void* d_out, int out_size, void* d_ws, size_t ws_size,
                              hipStream_t stream) {
  const float* hs     = (const float*)d_in[0];
  const float* qkv_w  = (const float*)d_in[1];
  const float* qkv_b  = (const float*)d_in[2];
  const float* proj_w = (const float*)d_in[3];
  const float* proj_b = (const float*)d_in[4];
  float* out = (float*)d_out;

  u16* hs_bf  = (u16*)d_ws;                 // 6291456 u16
  u16* qkvwT  = hs_bf  + 6291456;           // 884736
  u16* projwT = qkvwT  + 884736;            // 589824
  u16* vT     = projwT + 589824;            // 12582912 (32*96*4096)
  u16* kbuf   = vT     + 12582912;          // 12582912
  u16* spare  = kbuf   + 12582912;          // 12582912 (unused)
  u16* qpol   = spare  + 12582912;          // 3145728
  u16* aout   = qpol   + 3145728;           // 3145728

  prep<<<6504, 256, 0, stream>>>(hs, hs_bf, qkv_w, qkvwT, proj_w, projwT);

  gemm_bt<0><<<2304, 256, 0, stream>>>(hs_bf, qkvwT, qkv_b,
                                       qpol, kbuf, vT, nullptr, 384, 18, 288);
  flash7<<<512, 512, 0, stream>>>(qpol, kbuf, vT, aout);
  gemm_bt<1><<<192, 256, 0, stream>>>(aout, projwT, proj_b,
                                      nullptr, nullptr, nullptr, out, 768, 6, 24);
}

// Round 12
// 146.814 us; speedup vs baseline: 1.3549x; 1.0937x over previous
//
#include <hip/hip_runtime.h>
#include <hip/hip_bf16.h>

typedef unsigned short u16;
typedef __attribute__((ext_vector_type(8))) short bf16x8;
typedef __attribute__((ext_vector_type(8))) unsigned short u16x8;
typedef __attribute__((ext_vector_type(4))) float f32x4;

#define MFMA16(a,b,c) __builtin_amdgcn_mfma_f32_16x16x32_bf16(a,b,c,0,0,0)

__device__ __forceinline__ u16 f2bf(float f) {
  union { float f; unsigned int u; } v; v.f = f;
  unsigned int r = v.u + 0x7fffu + ((v.u >> 16) & 1u);  // RNE, finite inputs
  return (u16)(r >> 16);
}
__device__ __forceinline__ float bf2f(u16 u) {
  union { unsigned int i; float f; } v; v.i = ((unsigned int)u) << 16; return v.f;
}
__device__ __forceinline__ float exp2a(float x) {   // raw v_exp_f32 (args bounded)
  float r;
  asm("v_exp_f32 %0, %1" : "=v"(r) : "v"(x));
  return r;
}
__device__ __forceinline__ float max3(float a, float b, float c) {
  float r;
  asm("v_max3_f32 %0, %1, %2, %3" : "=v"(r) : "v"(a), "v"(b), "v"(c));
  return r;
}

__device__ __forceinline__ void gld16(const void* g, void* l) {
  __builtin_amdgcn_global_load_lds((const __attribute__((address_space(1))) void*)g,
                                   (__attribute__((address_space(3))) void*)l, 16, 0, 0);
}

// ---------------- fused prep: cast4 (blocks 0..6143) + ttrans qkv + ttrans proj ----------------
__device__ __forceinline__ void ttrans_body(const float* __restrict__ in, u16* __restrict__ out,
                                            int K, int N, int blk, int tid, u16 T[64][65]) {
  const int ntx = N >> 6;
  const int tx = blk % ntx, ty = blk / ntx;
  const int n0 = tx * 64, k0 = ty * 64;
  #pragma unroll
  for (int p = 0; p < 4; ++p) {
    int idx = p * 256 + tid;            // 0..1023
    int r = idx >> 4, ch = idx & 15;
    float4 v = *reinterpret_cast<const float4*>(in + (size_t)(k0 + r) * N + n0 + ch * 4);
    T[r][ch * 4 + 0] = f2bf(v.x);
    T[r][ch * 4 + 1] = f2bf(v.y);
    T[r][ch * 4 + 2] = f2bf(v.z);
    T[r][ch * 4 + 3] = f2bf(v.w);
  }
  __syncthreads();
  #pragma unroll
  for (int p = 0; p < 2; ++p) {
    int idx = p * 256 + tid;            // 0..511
    int rr = idx >> 3, ch = idx & 7;
    u16x8 o;
    #pragma unroll
    for (int e = 0; e < 8; ++e) o[e] = T[ch * 8 + e][rr];
    *reinterpret_cast<u16x8*>(out + (size_t)(n0 + rr) * K + k0 + ch * 8) = o;
  }
}

__global__ void prep(const float* __restrict__ hs, u16* __restrict__ hs_bf,
                     const float* __restrict__ qkv_w, u16* __restrict__ qkvwT,
                     const float* __restrict__ proj_w, u16* __restrict__ projwT) {
  __shared__ u16 T[64][65];
  const int blk = blockIdx.x, tid = threadIdx.x;
  if (blk < 6144) {
    int i = blk * 256 + tid;            // n4 = 1572864 = 6144*256 exact
    float4 v = reinterpret_cast<const float4*>(hs)[i];
    ushort4 o; o.x = f2bf(v.x); o.y = f2bf(v.y); o.z = f2bf(v.z); o.w = f2bf(v.w);
    reinterpret_cast<ushort4*>(hs_bf)[i] = o;
  } else if (blk < 6360) {
    ttrans_body(qkv_w, qkvwT, 384, 2304, blk - 6144, tid, T);
  } else {
    ttrans_body(proj_w, projwT, 768, 768, blk - 6360, tid, T);
  }
}

// ---------------- GEMM: C[M,N] = A[M,K] * Bt[N,K]^T + bias ----------------
// 128x128 tile, BK=32, dbuf LDS (single 32KB arena), counted-vmcnt prefetch, XCD swizzle.
// EPI 0 (qkv): q cols (bcol<768) -> fused 2x2 maxpool*SC -> qp (bf16);
//              k cols -> kbuf natural; v cols (bcol>=1536) -> in-LDS transpose -> vT
//              with per-64-key-tile column permutation pi (zero-transport PV in flash).
// EPI 1: fp32 out (proj).
template<int EPI>
__launch_bounds__(256)
__global__ void gemm_bt(const u16* __restrict__ A, const u16* __restrict__ Bt,
                        const float* __restrict__ bias,
                        u16* __restrict__ qp, u16* __restrict__ ok, u16* __restrict__ ov,
                        float* __restrict__ of, int K, int nbx, int cpx) {
  __shared__ __align__(16) u16 Sh[16384];   // As = Sh[0..8191], Bs = Sh[8192..16383]
  const int id = blockIdx.x;
  const int id2 = (id & 7) * cpx + (id >> 3);   // cpx = nwg/8
  const int bx = id2 % nbx, by = id2 / nbx;
  const int tid = threadIdx.x;
  const int wave = tid >> 6, lane = tid & 63;
  const int c = lane & 15, g = lane >> 4;
  const int brow = by * 128, bcol = bx * 128;
  const int wr = (wave >> 1) * 64, wc = (wave & 1) * 64;
  f32x4 acc[4][4] = {};
  const int srow = wave * 32 + (lane >> 2);
  const int scol = (lane & 3) * 8;
  const u16* agp0 = A  + (size_t)(brow + srow) * K + scol;
  const u16* agp1 = A  + (size_t)(brow + srow + 16) * K + scol;
  const u16* bgp0 = Bt + (size_t)(bcol + srow) * K + scol;
  const u16* bgp1 = Bt + (size_t)(bcol + srow + 16) * K + scol;
  const int lo0 = wave * 1024, lo1 = wave * 1024 + 512;
  const int nk = K >> 5;
  gld16(agp0, &Sh[lo0]);
  gld16(agp1, &Sh[lo1]);
  gld16(bgp0, &Sh[8192 + lo0]);
  gld16(bgp1, &Sh[8192 + lo1]);
  for (int ks = 0; ks < nk; ++ks) {
    const int cur = ks & 1;
    if (ks + 1 < nk) {
      const int k1 = (ks + 1) << 5;
      const int nb = (cur ^ 1) * 4096;
      gld16(agp0 + k1, &Sh[nb + lo0]);
      gld16(agp1 + k1, &Sh[nb + lo1]);
      gld16(bgp0 + k1, &Sh[8192 + nb + lo0]);
      gld16(bgp1 + k1, &Sh[8192 + nb + lo1]);
      asm volatile("s_waitcnt vmcnt(4)" ::: "memory");
    } else {
      asm volatile("s_waitcnt vmcnt(0)" ::: "memory");
    }
    __builtin_amdgcn_s_barrier();
    __builtin_amdgcn_sched_barrier(0);
    const int cb = cur * 4096;
    bf16x8 af[4], bfr[4];
    #pragma unroll
    for (int mi = 0; mi < 4; ++mi)
      af[mi] = *reinterpret_cast<const bf16x8*>(&Sh[cb + (wr + mi * 16 + c) * 32 + g * 8]);
    #pragma unroll
    for (int ni = 0; ni < 4; ++ni)
      bfr[ni] = *reinterpret_cast<const bf16x8*>(&Sh[8192 + cb + (wc + ni * 16 + c) * 32 + g * 8]);
    #pragma unroll
    for (int mi = 0; mi < 4; ++mi)
      #pragma unroll
      for (int ni = 0; ni < 4; ++ni)
        acc[mi][ni] = MFMA16(af[mi], bfr[ni], acc[mi][ni]);
    __builtin_amdgcn_sched_barrier(0);
    __builtin_amdgcn_s_barrier();
  }
  if (EPI == 0 && bcol < 768) {
    // ---- fused 2x2 maxpool: block = rows (h0,h0+1) x all w; pooled rows hq*32+wq ----
    const float SC = 0.14724744f;       // 96^-0.5 * log2(e)
    float* P = (float*)&Sh[0];          // [2][32][64] f32 = 16KB
    float m01[4][4], m23[4][4];
    #pragma unroll
    for (int mi = 0; mi < 4; ++mi)
      #pragma unroll
      for (int ni = 0; ni < 4; ++ni) {
        m01[mi][ni] = fmaxf(acc[mi][ni][0], acc[mi][ni][1]);
        m23[mi][ni] = fmaxf(acc[mi][ni][2], acc[mi][ni][3]);
      }
    if (wr == 64) {                     // h0+1 half: publish partials
      #pragma unroll
      for (int mi = 0; mi < 4; ++mi)
        #pragma unroll
        for (int ni = 0; ni < 4; ++ni) {
          const int pw = mi * 8 + g * 2;
          P[(wave & 1) * 2048 + pw * 64 + ni * 16 + c]       = m01[mi][ni];
          P[(wave & 1) * 2048 + (pw + 1) * 64 + ni * 16 + c] = m23[mi][ni];
        }
    }
    __syncthreads();
    if (wr == 0) {                      // h0 half: combine + write qpol
      const int b = brow >> 12;
      const int hq = (brow >> 7) & 31;
      const size_t rbase = (size_t)(b * 1024 + hq * 32);
      #pragma unroll
      for (int mi = 0; mi < 4; ++mi)
        #pragma unroll
        for (int ni = 0; ni < 4; ++ni) {
          const int col = bcol + wc + ni * 16 + c;
          const float bz = bias[col];
          const int pw = mi * 8 + g * 2;
          float v0 = fmaxf(m01[mi][ni], P[(wave & 1) * 2048 + pw * 64 + ni * 16 + c]);
          float v1 = fmaxf(m23[mi][ni], P[(wave & 1) * 2048 + (pw + 1) * 64 + ni * 16 + c]);
          qp[(rbase + pw) * 768 + col]     = f2bf((v0 + bz) * SC);
          qp[(rbase + pw + 1) * 768 + col] = f2bf((v1 + bz) * SC);
        }
    }
    return;
  }
  if (EPI == 0 && bcol >= 1536) {
    // ---- V epilogue: in-LDS transpose -> vT with per-64-tile key permutation ----
    u16* T = &Sh[0];
    const int vc0 = bcol - 1536;
    const int bq = brow >> 12;
    const int s0 = brow & 4095;
    #pragma unroll
    for (int ni = 0; ni < 4; ++ni) {
      const int j = wc + ni * 16 + c;
      const float bz = bias[bcol + j];
      const int key = (j & 15) << 2;
      #pragma unroll
      for (int mi = 0; mi < 4; ++mi) {
        const int rb = wr + mi * 16 + g * 4;
        ushort4 o;
        o.x = f2bf(acc[mi][ni][0] + bz);
        o.y = f2bf(acc[mi][ni][1] + bz);
        o.z = f2bf(acc[mi][ni][2] + bz);
        o.w = f2bf(acc[mi][ni][3] + bz);
        *reinterpret_cast<ushort4*>(&T[j * 128 + (rb ^ key)]) = o;
      }
    }
    __syncthreads();
    u16* vb2 = ov + ((size_t)(bq * 768 + vc0)) * 4096 + s0;
    #pragma unroll
    for (int p = 0; p < 8; ++p) {
      const int j = p * 16 + wave * 4 + (lane >> 4);
      const int sc = lane & 15;
      const int key = j & 15;
      const int p4 = 8 * (sc >> 3) + 2 * (sc & 3) + ((sc >> 2) & 1);
      uint2 lo = *reinterpret_cast<uint2*>(&T[j * 128 + ((sc ^ key) << 2)]);
      uint2 hi = *reinterpret_cast<uint2*>(&T[j * 128 + (((sc + 16) ^ key) << 2)]);
      *reinterpret_cast<uint2*>(vb2 + (size_t)j * 4096 + p4 * 4)      = lo;
      *reinterpret_cast<uint2*>(vb2 + (size_t)j * 4096 + 64 + p4 * 4) = hi;
    }
    return;
  }
  #pragma unroll
  for (int mi = 0; mi < 4; ++mi) {
    #pragma unroll
    for (int ni = 0; ni < 4; ++ni) {
      const int col = bcol + wc + ni * 16 + c;
      const float bz = bias[col];
      #pragma unroll
      for (int i = 0; i < 4; ++i) {
        const int row = brow + wr + mi * 16 + g * 4 + i;
        float v = acc[mi][ni][i] + bz;
        if (EPI == 0) {
          ok[(size_t)row * 768 + col - 768] = f2bf(v);
        } else {
          of[(size_t)row * 768 + col] = v;
        }
      }
    }
  }
}

// ---------------- flash attention: 8 waves, in-block key-split + combine, XCD-grouped ----------------
// grid 512, XCD remap: x=blk&7, j=blk>>3 -> bh = x + 8*(j>>4), qt = j&15.
// Zero-LDS P transport (vT key permutation); VALU-diet softmax (raw v_exp, max3, zero-C MFMA).
// LDS 48KB: K0@0, V0@6144, K1@12288, V1@18432 (u16 idx).
__launch_bounds__(512, 4)
__global__ void flash8(const u16* __restrict__ Qp, const u16* __restrict__ Kb,
                       const u16* __restrict__ Vtg, u16* __restrict__ aout) {
  const int blk = blockIdx.x;
  const int xcd = blk & 7, j = blk >> 3;
  const int bh = xcd + 8 * (j >> 4), qt = j & 15;
  const int b = bh >> 3, h = bh & 7;
  __shared__ __align__(16) u16 Sh[24576];
  const int tid = threadIdx.x, w = tid >> 6, lane = tid & 63;
  const int sq = w >> 2, wq = w & 3;
  const int c = lane & 15, g = lane >> 4;
  const int kbase = sq * 12288;
  const int vbase = 6144 + sq * 12288;
  const u16* qb = Qp + ((size_t)(b * 1024 + qt * 64 + wq * 16 + c)) * 768 + h * 96;
  bf16x8 qf[3];
  #pragma unroll
  for (int kc = 0; kc < 3; ++kc)
    qf[kc] = *reinterpret_cast<const bf16x8*>(qb + kc * 32 + g * 8);
  const u16* kp[3];
  const u16* vp[3];
  int loff[3];
  {
    const u16* kb0 = Kb + ((size_t)(b * 4096 + sq * 2048)) * 768 + h * 96;
    const u16* vb0 = Vtg + ((size_t)(bh * 96)) * 4096 + sq * 2048;
    #pragma unroll
    for (int j2 = 0; j2 < 3; ++j2) {
      int p = wq * 192 + j2 * 64 + lane;  // 0..767
      int r = p / 12, ch = p - r * 12;
      kp[j2] = kb0 + r * 768 + ch * 8;
      int d = p >> 3, vch = p & 7;
      vp[j2] = vb0 + d * 4096 + ((vch ^ (d & 7)) * 8);
      loff[j2] = (wq * 192 + j2 * 64) * 8;
    }
  }
  float m = -1e30f, l = 0.f;
  f32x4 acc[6] = {};
  const f32x4 z4 = {0.f, 0.f, 0.f, 0.f};
  const int sw = (c & 7) << 3;
  for (int kt = 0; kt < 32; ++kt) {
    __syncthreads();
    #pragma unroll
    for (int j2 = 0; j2 < 3; ++j2) gld16(kp[j2], &Sh[kbase + loff[j2]]);
    #pragma unroll
    for (int j2 = 0; j2 < 3; ++j2) gld16(vp[j2], &Sh[vbase + loff[j2]]);
    #pragma unroll
    for (int j2 = 0; j2 < 3; ++j2) { kp[j2] += 49152; vp[j2] += 64; }
    __syncthreads();
    // swapped QK^T; first MFMA uses C=0 (no zero-fill moves)
    f32x4 st[4];
    __builtin_amdgcn_s_setprio(1);
    #pragma unroll
    for (int kt4 = 0; kt4 < 4; ++kt4) {
      bf16x8 kf = *reinterpret_cast<const bf16x8*>(&Sh[kbase + (kt4 * 16 + c) * 96 + g * 8]);
      st[kt4] = MFMA16(kf, qf[0], z4);
    }
    #pragma unroll
    for (int kc = 1; kc < 3; ++kc)
      #pragma unroll
      for (int kt4 = 0; kt4 < 4; ++kt4) {
        bf16x8 kf = *reinterpret_cast<const bf16x8*>(&Sh[kbase + (kt4 * 16 + c) * 96 + kc * 32 + g * 8]);
        st[kt4] = MFMA16(kf, qf[kc], st[kt4]);
      }
    __builtin_amdgcn_s_setprio(0);
    // row max: max3 tree (8 inst) + 2 shfl
    float pmax;
    {
      float a0 = max3(st[0][0], st[0][1], st[0][2]);
      float a1 = max3(st[0][3], st[1][0], st[1][1]);
      float a2 = max3(st[1][2], st[1][3], st[2][0]);
      float a3 = max3(st[2][1], st[2][2], st[2][3]);
      float a4 = max3(st[3][0], st[3][1], st[3][2]);
      pmax = fmaxf(max3(a0, a1, st[3][3]), max3(a2, a3, a4));
    }
    pmax = fmaxf(pmax, __shfl_xor(pmax, 16));
    pmax = fmaxf(pmax, __shfl_xor(pmax, 32));
    if (__any(pmax > m + 8.0f)) {
      float mn = fmaxf(m, pmax);
      float esc = exp2a(m - mn);
      m = mn;
      l *= esc;
      float er[4];
      #pragma unroll
      for (int i = 0; i < 4; ++i) er[i] = __shfl(esc, g * 4 + i);
      #pragma unroll
      for (int dc = 0; dc < 6; ++dc)
        #pragma unroll
        for (int i = 0; i < 4; ++i)
          acc[dc][i] *= er[i];
    }
    float ps = 0.f;
    #pragma unroll
    for (int kt4 = 0; kt4 < 4; ++kt4)
      #pragma unroll
      for (int i = 0; i < 4; ++i) {
        float p = exp2a(st[kt4][i] - m);
        st[kt4][i] = p;
        ps += p;
      }
    ps += __shfl_xor(ps, 16);
    ps += __shfl_xor(ps, 32);
    l += ps;
    // pack P in-lane (vT key permutation makes PV A-frag in-lane)
    unsigned int uu[4][2];
    #pragma unroll
    for (int kt4 = 0; kt4 < 4; ++kt4) {
      asm("v_cvt_pk_bf16_f32 %0, %1, %2" : "=v"(uu[kt4][0]) : "v"(st[kt4][0]), "v"(st[kt4][1]));
      asm("v_cvt_pk_bf16_f32 %0, %1, %2" : "=v"(uu[kt4][1]) : "v"(st[kt4][2]), "v"(st[kt4][3]));
    }
    __builtin_amdgcn_s_setprio(1);
    #pragma unroll
    for (int kh = 0; kh < 2; ++kh) {
      union { unsigned int wrd[4]; bf16x8 v; } pfu;
      pfu.wrd[0] = uu[2 * kh][0];
      pfu.wrd[1] = uu[2 * kh][1];
      pfu.wrd[2] = uu[2 * kh + 1][0];
      pfu.wrd[3] = uu[2 * kh + 1][1];
      bf16x8 pf = pfu.v;
      #pragma unroll
      for (int dc = 0; dc < 6; ++dc) {
        bf16x8 vf = *reinterpret_cast<const bf16x8*>(&Sh[vbase + (dc * 16 + c) * 64 + ((kh * 32 + g * 8) ^ sw)]);
        acc[dc] = MFMA16(pf, vf, acc[dc]);
      }
    }
    __builtin_amdgcn_s_setprio(0);
  }
  // ---- in-block combine of the two key-halves ----
  __syncthreads();
  float* Cb = (float*)&Sh[0];            // [4][16][96] f32 = 24KB (overlays K0/V0)
  float* Ml = (float*)&Sh[12288];        // [4][16][2] f32 (overlays K1)
  if (sq == 1) {
    #pragma unroll
    for (int dc = 0; dc < 6; ++dc)
      #pragma unroll
      for (int i = 0; i < 4; ++i)
        Cb[(wq * 16 + g * 4 + i) * 96 + dc * 16 + c] = acc[dc][i];
    if (lane < 16) {
      Ml[(wq * 16 + lane) * 2]     = m;
      Ml[(wq * 16 + lane) * 2 + 1] = l;
    }
  }
  __syncthreads();
  if (sq == 0) {
    u16* ob = aout + (size_t)(b * 1024 + qt * 64 + wq * 16) * 768 + h * 96;
    #pragma unroll
    for (int i = 0; i < 4; ++i) {
      const int q = g * 4 + i;
      float m0q = __shfl(m, q), l0q = __shfl(l, q);
      float m1q = Ml[(wq * 16 + q) * 2], l1q = Ml[(wq * 16 + q) * 2 + 1];
      float M = fmaxf(m0q, m1q);
      float e0 = exp2a(m0q - M), e1 = exp2a(m1q - M);
      float inv = 1.f / (l0q * e0 + l1q * e1);
      #pragma unroll
      for (int dc = 0; dc < 6; ++dc) {
        float a1 = Cb[(wq * 16 + q) * 96 + dc * 16 + c];
        ob[(size_t)q * 768 + dc * 16 + c] = f2bf((acc[dc][i] * e0 + a1 * e1) * inv);
      }
    }
  }
}

extern "C" void kernel_launch(void* const* d_in, const int* in_sizes, int n_in,
                              void* d_out, int out_size, void* d_ws, size_t ws_size,
                              hipStream_t stream) {
  const float* hs     = (const float*)d_in[0];
  const float* qkv_w  = (const float*)d_in[1];
  const float* qkv_b  = (const float*)d_in[2];
  const float* proj_w = (const float*)d_in[3];
  const float* proj_b = (const float*)d_in[4];
  float* out = (float*)d_out;

  u16* hs_bf  = (u16*)d_ws;                 // 6291456 u16
  u16* qkvwT  = hs_bf  + 6291456;           // 884736
  u16* projwT = qkvwT  + 884736;            // 589824
  u16* vT     = projwT + 589824;            // 12582912 (32*96*4096)
  u16* kbuf   = vT     + 12582912;          // 12582912
  u16* spare  = kbuf   + 12582912;          // 12582912 (unused)
  u16* qpol   = spare  + 12582912;          // 3145728
  u16* aout   = qpol   + 3145728;           // 3145728

  prep<<<6504, 256, 0, stream>>>(hs, hs_bf, qkv_w, qkvwT, proj_w, projwT);

  gemm_bt<0><<<2304, 256, 0, stream>>>(hs_bf, qkvwT, qkv_b,
                                       qpol, kbuf, vT, nullptr, 384, 18, 288);
  flash8<<<512, 512, 0, stream>>>(qpol, kbuf, vT, aout);
  gemm_bt<1><<<192, 256, 0, stream>>>(aout, projwT, proj_b,
                                      nullptr, nullptr, nullptr, out, 768, 6, 24);
}